// Round 8
// baseline (1080.826 us; speedup 1.0000x reference)
//
#include <hip/hip_runtime.h>
#include <hip/hip_bf16.h>
#include <math.h>

#define NEG_SLOPE 0.2f
#define RBITS 8
#define RNODES 256          // nodes per bucket
#define CHUNK 8192          // edges per binning block
#define CAP   9216          // per-bucket region capacity (mean 8440 + ~8 sigma)
#define HS    32            // hb row stride in uints (128 B = 1 line, row-aligned)
#define NBATCH 4            // nodes per queue grab (gat)

// ---------------- helpers ----------------

__device__ __forceinline__ float waveReduceSum(float v) {
    #pragma unroll
    for (int off = 32; off > 0; off >>= 1) v += __shfl_xor(v, off);
    return v;
}

__device__ __forceinline__ unsigned pack_bf16(float a, float b) {
    __hip_bfloat162 p(__float2bfloat16(a), __float2bfloat16(b));
    return *reinterpret_cast<unsigned*>(&p);
}
__device__ __forceinline__ float bf16lo_f(unsigned u) { return __uint_as_float(u << 16); }
__device__ __forceinline__ float bf16hi_f(unsigned u) { return __uint_as_float(u & 0xFFFF0000u); }

// ---------------- fused prep: WT1, WT2 transpose + bcursor/queue zero ----------------

__global__ void prep(const float* __restrict__ W1, float* __restrict__ WT1,
                     const float* __restrict__ W2, float* __restrict__ WT2,
                     int* __restrict__ bcursor,
                     int K1, int F1, int KP1, int FP1,
                     int K2, int F2, int KP2, int FP2, int NBZ) {
    int i = blockIdx.x * blockDim.x + threadIdx.x;
    int z1 = FP1 * KP1, z2 = FP2 * KP2;
    if (i < z1) {
        int f = i / KP1, k = i - f * KP1;
        WT1[i] = (f < F1 && k < K1) ? W1[k * F1 + f] : 0.f;
    } else if (i < z1 + z2) {
        int j = i - z1;
        int f = j / KP2, k = j - f * KP2;
        WT2[j] = (f < F2 && k < K2) ? W2[k * F2 + f] : 0.f;
    } else if (i < z1 + z2 + NBZ) {
        bcursor[i - z1 - z2] = 0;     // NB bucket cursors + 2 gat queue counters
    }
}

// ---------------- CSR build ----------------

// bin edges into fixed-capacity bucket regions; pack (dst&255)<<17 | src
__global__ __launch_bounds__(512) void binning(
        const int* __restrict__ src, const int* __restrict__ dst,
        int* __restrict__ bcursor, int* __restrict__ binned,
        long E, int N, long TOT) {
    __shared__ int hist[512];
    __shared__ int base[512];
    int t = threadIdx.x;
    hist[t] = 0;
    __syncthreads();
    long c0 = blockIdx.x * (long)CHUNK;
    long c1 = c0 + CHUNK; if (c1 > TOT) c1 = TOT;
    for (long i = c0 + t; i < c1; i += 512) {
        int d = (i < E) ? dst[i] : (int)(i - E);
        atomicAdd(&hist[d >> RBITS], 1);
    }
    __syncthreads();
    {
        int c = hist[t];
        base[t] = c ? atomicAdd(&bcursor[t], c) : 0;
        hist[t] = 0;
    }
    __syncthreads();
    for (long i = c0 + t; i < c1; i += 512) {
        int s, d;
        if (i < E) { s = src[i]; d = dst[i]; } else { s = d = (int)(i - E); }
        int b = d >> RBITS;
        int p = base[b] + atomicAdd(&hist[b], 1);
        if (p >= CAP) p = CAP - 1;   // safety clamp (never hit for this input)
        binned[(long)b * CAP + p] = ((d & (RNODES - 1)) << 17) | s;
    }
}

// single block (512 thr): exclusive scan of bucket counts (bcursor) -> bstarts[0..NB]
__global__ __launch_bounds__(512) void bucket_scan(
        const int* __restrict__ bcursor, int* __restrict__ bstarts,
        int* __restrict__ starts, int NB, int N, int TOT) {
    __shared__ int s[512];
    int t = threadIdx.x;
    int v = (t < NB) ? bcursor[t] : 0;
    s[t] = v;
    __syncthreads();
    for (int off = 1; off < 512; off <<= 1) {
        int u = (t >= off) ? s[t - off] : 0;
        __syncthreads();
        s[t] += u;
        __syncthreads();
    }
    int excl = s[t] - v;
    if (t < NB) bstarts[t] = excl;
    if (t == 0) { bstarts[NB] = TOT; starts[N] = TOT; }
}

// one block (512 thr) per bucket: per-node counts, LDS scan -> starts, compacting scatter
__global__ __launch_bounds__(512) void bucket_csr(
        const int* __restrict__ binned, const int* __restrict__ bstarts,
        int* __restrict__ starts, int* __restrict__ csr_src, int N) {
    __shared__ int cnt[RNODES];
    __shared__ int scn[RNODES];
    int b = blockIdx.x, t = threadIdx.x;
    int node0 = b << RBITS;
    int R = N - node0; if (R > RNODES) R = RNODES;
    int e0 = bstarts[b];
    int ecnt = bstarts[b + 1] - e0;
    const int* bin = binned + (long)b * CAP;
    if (t < RNODES) cnt[t] = 0;
    __syncthreads();
    for (int i = t; i < ecnt; i += 512)
        atomicAdd(&cnt[bin[i] >> 17], 1);
    __syncthreads();
    int v = (t < RNODES) ? cnt[t] : 0;
    if (t < RNODES) scn[t] = v;
    __syncthreads();
    for (int off = 1; off < RNODES; off <<= 1) {
        int u = (t >= off && t < RNODES) ? scn[t - off] : 0;
        __syncthreads();
        if (t < RNODES) scn[t] += u;
        __syncthreads();
    }
    if (t < RNODES) {
        int excl = scn[t] - v;
        if (t < R) starts[node0 + t] = e0 + excl;
        cnt[t] = excl;   // reuse as cursor
    }
    __syncthreads();
    for (int i = t; i < ecnt; i += 512) {
        int packed = bin[i];
        int ld = packed >> 17;
        int p = atomicAdd(&cnt[ld], 1);
        csr_src[e0 + p] = packed & 0x1FFFF;
    }
}

// ---------------- GEMM: lane=node, scalar W, LDS-transposed x ----------------
// block = 512 thr = 8 waves; 64-node tile; wave w computes features 8w..8w+7.
// hb rows zero-padded through uint FPH-1 (acc==0 for f>=F since WT zero-padded).
template <int K, int KP, int F, int FPH>
__global__ __launch_bounds__(512) void gemm_tile(
        const float* __restrict__ x, const float* __restrict__ WT,
        const float* __restrict__ att_s, const float* __restrict__ att_d,
        unsigned* __restrict__ hb, float* __restrict__ as_, float* __restrict__ ad_,
        int N) {
    __shared__ float xT[KP * 65];
    __shared__ float asl[64], adl[64];
    int t = threadIdx.x;
    int lane = t & 63;
    int w = t >> 6;
    long n0 = (long)blockIdx.x * 64;
    int n = (int)n0 + lane;

    if (t < 64) { asl[t] = 0.f; adl[t] = 0.f; }
    for (int idx = t; idx < KP * 64; idx += 512) {
        int nn = idx / KP, k = idx - nn * KP;
        float v = 0.f;
        if (k < K && n0 + nn < N) v = x[(n0 + nn) * (long)K + k];
        xT[k * 65 + nn] = v;
    }
    __syncthreads();

    int f0 = __builtin_amdgcn_readfirstlane(w * 8);
    float acc[8] = {0.f, 0.f, 0.f, 0.f, 0.f, 0.f, 0.f, 0.f};
    if (f0 < F) {
        const float* wbase = WT + (long)f0 * KP;
        for (int k0 = 0; k0 < KP; k0 += 4) {
            float x0 = xT[(k0 + 0) * 65 + lane];
            float x1 = xT[(k0 + 1) * 65 + lane];
            float x2 = xT[(k0 + 2) * 65 + lane];
            float x3 = xT[(k0 + 3) * 65 + lane];
            #pragma unroll
            for (int j = 0; j < 8; ++j) {
                const float* wr = wbase + j * KP + k0;   // wave-uniform -> s_load
                float a = acc[j];
                a = fmaf(wr[0], x0, a);
                a = fmaf(wr[1], x1, a);
                a = fmaf(wr[2], x2, a);
                a = fmaf(wr[3], x3, a);
                acc[j] = a;
            }
        }
        float ps = 0.f, pd = 0.f;
        #pragma unroll
        for (int j = 0; j < 8; ++j) {
            float sa = (f0 + j < F) ? att_s[f0 + j] : 0.f;
            float da = (f0 + j < F) ? att_d[f0 + j] : 0.f;
            ps = fmaf(acc[j], sa, ps);
            pd = fmaf(acc[j], da, pd);
        }
        atomicAdd(&asl[lane], ps);
        atomicAdd(&adl[lane], pd);
    }
    __syncthreads();

    if (f0 < F && n < N) {
        int f0h = f0 >> 1;
        #pragma unroll
        for (int q = 0; q < 4; ++q) {
            int fp = f0h + q;
            if (fp < FPH) hb[(long)n * HS + fp] = pack_bf16(acc[2 * q], acc[2 * q + 1]);
        }
    }
    if (w == 0 && n < N) { as_[n] = asl[lane]; ad_[n] = adl[lane]; }
}

// ---------------- gat gather ----------------
// one wave per dst node, nodes pulled in NBATCH-sized batches from a global
// atomic queue: no wave-slot stranding from degree variance (fixed node->wave
// mapping left finished waves idle until their block's max-degree wave
// retired -- measured as the persistent ~25% occupancy gap, r0-r7).
// Per-node body is the round-3 form verbatim: phase-A batched w computation
// (overlaps gathers; r5/r7 lesson), octet uint4 gathers, degree-matched work
// (r2 lesson), no min-waves clause (r1 lesson), no extra pass (r6 lesson).
template <int F>
__global__ __launch_bounds__(256) void gat_gather(
                           const int* __restrict__ csr_src, const int* __restrict__ starts,
                           const float* __restrict__ as_, const float* __restrict__ ad_,
                           const unsigned* __restrict__ hb, const float* __restrict__ bias,
                           float* __restrict__ out, int N, int* __restrict__ qc) {
    constexpr int NU4 = (F + 7) / 8;        // uint4 per row: 7 (F=50) / 5 (F=40)
    int lane = threadIdx.x & 63;
    int g  = lane >> 3;                     // octet (edge slot) 0..7
    int fl = lane & 7;                      // feature lane
    bool actf = (fl < NU4);
    const unsigned* hbase = hb + 4 * fl;    // lane-fixed feature offset (16B aligned)

    for (;;) {
        int b;
        if (lane == 0) b = atomicAdd(qc, 1);
        b = __shfl(b, 0);
        int nlo = b * NBATCH;
        if (nlo >= N) break;
        int nhi = nlo + NBATCH; if (nhi > N) nhi = N;

        for (int d = nlo; d < nhi; ++d) {
            int s0 = starts[d], s1 = starts[d + 1];
            float add = ad_[d];

            float lsum = 0.f;
            float a0 = 0.f, a1 = 0.f, a2 = 0.f, a3 = 0.f;
            float a4 = 0.f, a5 = 0.f, a6 = 0.f, a7 = 0.f;

            for (int base = s0; base < s1; base += 64) {
                int k = base + lane;
                int s = (k < s1) ? csr_src[k] : 0;    // invalid lanes -> row 0 (w=0)
                unsigned soff = (unsigned)s * HS;     // row offset in uints
                float e = as_[s] + add;
                e = e > 0.f ? e : NEG_SLOPE * e;
                float w = (k < s1) ? __expf(e) : 0.f;
                lsum += w;
                int cnt = min(64, s1 - base);
                int nst = (cnt + 7) >> 3;             // octet steps (1..8)
                int j = 0;
                for (; j + 4 <= nst; j += 4) {
                    int i0 = 8 * j + g;
                    unsigned so0 = __shfl(soff, i0);
                    unsigned so1 = __shfl(soff, i0 + 8);
                    unsigned so2 = __shfl(soff, i0 + 16);
                    unsigned so3 = __shfl(soff, i0 + 24);
                    uint4 h0 = make_uint4(0u,0u,0u,0u), h1 = h0, h2 = h0, h3 = h0;
                    if (actf) {
                        h0 = *(const uint4*)(hbase + so0);
                        h1 = *(const uint4*)(hbase + so1);
                        h2 = *(const uint4*)(hbase + so2);
                        h3 = *(const uint4*)(hbase + so3);
                    }
                    float w0 = __shfl(w, i0);
                    float w1 = __shfl(w, i0 + 8);
                    float w2 = __shfl(w, i0 + 16);
                    float w3 = __shfl(w, i0 + 24);
                    a0 = fmaf(w0, bf16lo_f(h0.x), a0); a1 = fmaf(w0, bf16hi_f(h0.x), a1);
                    a2 = fmaf(w0, bf16lo_f(h0.y), a2); a3 = fmaf(w0, bf16hi_f(h0.y), a3);
                    a4 = fmaf(w0, bf16lo_f(h0.z), a4); a5 = fmaf(w0, bf16hi_f(h0.z), a5);
                    a6 = fmaf(w0, bf16lo_f(h0.w), a6); a7 = fmaf(w0, bf16hi_f(h0.w), a7);
                    a0 = fmaf(w1, bf16lo_f(h1.x), a0); a1 = fmaf(w1, bf16hi_f(h1.x), a1);
                    a2 = fmaf(w1, bf16lo_f(h1.y), a2); a3 = fmaf(w1, bf16hi_f(h1.y), a3);
                    a4 = fmaf(w1, bf16lo_f(h1.z), a4); a5 = fmaf(w1, bf16hi_f(h1.z), a5);
                    a6 = fmaf(w1, bf16lo_f(h1.w), a6); a7 = fmaf(w1, bf16hi_f(h1.w), a7);
                    a0 = fmaf(w2, bf16lo_f(h2.x), a0); a1 = fmaf(w2, bf16hi_f(h2.x), a1);
                    a2 = fmaf(w2, bf16lo_f(h2.y), a2); a3 = fmaf(w2, bf16hi_f(h2.y), a3);
                    a4 = fmaf(w2, bf16lo_f(h2.z), a4); a5 = fmaf(w2, bf16hi_f(h2.z), a5);
                    a6 = fmaf(w2, bf16lo_f(h2.w), a6); a7 = fmaf(w2, bf16hi_f(h2.w), a7);
                    a0 = fmaf(w3, bf16lo_f(h3.x), a0); a1 = fmaf(w3, bf16hi_f(h3.x), a1);
                    a2 = fmaf(w3, bf16lo_f(h3.y), a2); a3 = fmaf(w3, bf16hi_f(h3.y), a3);
                    a4 = fmaf(w3, bf16lo_f(h3.z), a4); a5 = fmaf(w3, bf16hi_f(h3.z), a5);
                    a6 = fmaf(w3, bf16lo_f(h3.w), a6); a7 = fmaf(w3, bf16hi_f(h3.w), a7);
                }
                for (; j < nst; ++j) {
                    int idx = 8 * j + g;
                    float wp = __shfl(w, idx);
                    unsigned so = __shfl(soff, idx);
                    if (actf) {
                        uint4 hv = *(const uint4*)(hbase + so);
                        a0 = fmaf(wp, bf16lo_f(hv.x), a0); a1 = fmaf(wp, bf16hi_f(hv.x), a1);
                        a2 = fmaf(wp, bf16lo_f(hv.y), a2); a3 = fmaf(wp, bf16hi_f(hv.y), a3);
                        a4 = fmaf(wp, bf16lo_f(hv.z), a4); a5 = fmaf(wp, bf16hi_f(hv.z), a5);
                        a6 = fmaf(wp, bf16lo_f(hv.w), a6); a7 = fmaf(wp, bf16hi_f(hv.w), a7);
                    }
                }
            }

            // combine the eight octet partials
            #pragma unroll
            for (int off = 8; off < 64; off <<= 1) {
                a0 += __shfl_xor(a0, off); a1 += __shfl_xor(a1, off);
                a2 += __shfl_xor(a2, off); a3 += __shfl_xor(a3, off);
                a4 += __shfl_xor(a4, off); a5 += __shfl_xor(a5, off);
                a6 += __shfl_xor(a6, off); a7 += __shfl_xor(a7, off);
            }
            float l = waveReduceSum(lsum);

            if (actf && g == 0) {
                float inv = 1.f / l;
                int fb = 8 * fl;
                float v[8] = {a0, a1, a2, a3, a4, a5, a6, a7};
                float2* orow = (float2*)(out + (long)d * F + fb);   // 8B-aligned (F even)
                #pragma unroll
                for (int i = 0; i < 8; i += 2) {
                    if (fb + i < F) {            // F even -> pair fully valid
                        float u0 = v[i]     * inv + bias[fb + i];
                        float u1 = v[i + 1] * inv + bias[fb + i + 1];
                        u0 = u0 > 0.f ? u0 : 0.f;
                        u1 = u1 > 0.f ? u1 : 0.f;
                        orow[i >> 1] = make_float2(u0, u1);
                    }
                }
            }
        }
    }
}

// edge_index passthrough as float (vectorized)
__global__ void copy_edges4(const int4* __restrict__ ei, float4* __restrict__ out, long n4) {
    long i = blockIdx.x * (long)blockDim.x + threadIdx.x;
    if (i < n4) {
        int4 v = ei[i];
        out[i] = make_float4((float)v.x, (float)v.y, (float)v.z, (float)v.w);
    }
}
__global__ void copy_edges_tail(const int* __restrict__ ei, float* __restrict__ out,
                                long lo, long n) {
    long i = lo + blockIdx.x * (long)blockDim.x + threadIdx.x;
    if (i < n) out[i] = (float)ei[i];
}

// ---------------- launch ----------------

extern "C" void kernel_launch(void* const* d_in, const int* in_sizes, int n_in,
                              void* d_out, int out_size, void* d_ws, size_t ws_size,
                              hipStream_t stream) {
    const float* x         = (const float*)d_in[0];
    const int*   edge_idx  = (const int*)d_in[1];
    const float* W1        = (const float*)d_in[2];
    const float* att_src1  = (const float*)d_in[3];
    const float* att_dst1  = (const float*)d_in[4];
    const float* bias1     = (const float*)d_in[5];
    const float* W2        = (const float*)d_in[6];
    const float* att_src2  = (const float*)d_in[7];
    const float* att_dst2  = (const float*)d_in[8];
    const float* bias2     = (const float*)d_in[9];

    const int  CIN = 128, F1 = 50, F2 = 40;
    const int  KP1 = 128, FP1 = 56;            // padded W1T dims
    const int  KP2 = 52,  FP2 = 40;            // padded W2T dims
    const int  N = in_sizes[0] / CIN;          // 100000
    const long E = in_sizes[1] / 2;            // 3200000
    const int* src = edge_idx;
    const int* dst = edge_idx + E;
    const long TOT = E + N;                    // edges incl self-loops
    const int  NB = (N + RNODES - 1) >> RBITS; // 391 buckets (<=512)

    // ---- workspace layout ----
    char* wsb = (char*)d_ws;
    size_t regionA = (size_t)NB * CAP * 4;                        // 14.4 MB
    if ((size_t)N * HS * 4 > regionA) regionA = (size_t)N * HS * 4;
    int*      binned = (int*)wsb;
    unsigned* hb     = (unsigned*)wsb;
    float*    hout   = (float*)(wsb + regionA);         // N*F1 floats (20 MB)
    float*    as_    = hout + (long)N * F1;             // N
    float*    ad_    = as_ + N;                         // N
    int*      starts  = (int*)(ad_ + N);                // N+1
    int*      csr_src = starts + (N + 1);               // TOT
    int*      bstarts = csr_src + TOT;                  // NB+1
    int*      bcursor = bstarts + (NB + 1);             // NB + 2 queue counters
    int*      qc1     = bcursor + NB;                   // layer-1 gat queue
    int*      qc2     = bcursor + NB + 1;               // layer-2 gat queue
    float*    WT1     = (float*)(bcursor + NB + 3);     // FP1*KP1
    float*    WT2     = WT1 + FP1 * KP1;                // FP2*KP2

    float* out_h = (float*)d_out;              // N*F2
    float* out_e = out_h + (long)N * F2;       // 2*E

    const int B = 256;
    const int gatBlocks = 2048;                // persistent-ish: 8192 waves pull from queue
    const int nTileBlocks = (N + 63) / 64;     // gemm: 64-node tiles
    const int nBinBlocks = (int)((TOT + CHUNK - 1) / CHUNK);
    const int prepElems = FP1 * KP1 + FP2 * KP2 + NB + 2;

    // ---- prep (WT transposes + cursor/queue zero) + CSR build ----
    prep<<<dim3((prepElems + B - 1) / B), dim3(B), 0, stream>>>(
        W1, WT1, W2, WT2, bcursor, CIN, F1, KP1, FP1, F1, F2, KP2, FP2, NB + 2);
    binning<<<dim3(nBinBlocks), dim3(512), 0, stream>>>(src, dst, bcursor, binned, E, N, TOT);
    bucket_scan<<<dim3(1), dim3(512), 0, stream>>>(bcursor, bstarts, starts, NB, N, (int)TOT);
    bucket_csr<<<dim3(NB), dim3(512), 0, stream>>>(binned, bstarts, starts, csr_src, N);

    // ---- layer 1 ----
    gemm_tile<CIN, KP1, F1, FP1 / 2><<<dim3(nTileBlocks), dim3(512), 0, stream>>>(
        x, WT1, att_src1, att_dst1, hb, as_, ad_, N);
    gat_gather<F1><<<dim3(gatBlocks), dim3(B), 0, stream>>>(
        csr_src, starts, as_, ad_, hb, bias1, hout, N, qc1);

    // ---- layer 2 ----
    gemm_tile<F1, KP2, F2, FP2 / 2><<<dim3(nTileBlocks), dim3(512), 0, stream>>>(
        hout, WT2, att_src2, att_dst2, hb, as_, ad_, N);
    gat_gather<F2><<<dim3(gatBlocks), dim3(B), 0, stream>>>(
        csr_src, starts, as_, ad_, hb, bias2, out_h, N, qc2);

    // ---- edge_index passthrough ----
    long n_e = 2 * E;
    long n4  = n_e / 4;
    copy_edges4<<<dim3((int)((n4 + B - 1) / B)), dim3(B), 0, stream>>>((const int4*)edge_idx, (float4*)out_e, n4);
    if (n_e - n4 * 4 > 0)
        copy_edges_tail<<<dim3(1), dim3(B), 0, stream>>>(edge_idx, out_e, n4 * 4, n_e);
}

// Round 9
// 419.984 us; speedup vs baseline: 2.5735x; 2.5735x over previous
//
#include <hip/hip_runtime.h>
#include <hip/hip_bf16.h>
#include <math.h>

#define NEG_SLOPE 0.2f
#define RBITS 8
#define RNODES 256          // nodes per bucket
#define CHUNK 8192          // edges per binning block
#define CAP   9216          // per-bucket region capacity (mean 8440 + ~8 sigma)
#define HS    32            // hb row stride in uints (128 B = 1 line, row-aligned)
#define NBATCH 4            // nodes per queue grab (gat)
#define QPARTS 64           // gat queue partitions (separate counters)
#define QSTRIDE 32          // ints between counters (128 B -> no line sharing)

// ---------------- helpers ----------------

__device__ __forceinline__ float waveReduceSum(float v) {
    #pragma unroll
    for (int off = 32; off > 0; off >>= 1) v += __shfl_xor(v, off);
    return v;
}

__device__ __forceinline__ unsigned pack_bf16(float a, float b) {
    __hip_bfloat162 p(__float2bfloat16(a), __float2bfloat16(b));
    return *reinterpret_cast<unsigned*>(&p);
}
__device__ __forceinline__ float bf16lo_f(unsigned u) { return __uint_as_float(u << 16); }
__device__ __forceinline__ float bf16hi_f(unsigned u) { return __uint_as_float(u & 0xFFFF0000u); }

// ---------------- fused prep: WT1, WT2 transpose + bcursor/queue zero ----------------

__global__ void prep(const float* __restrict__ W1, float* __restrict__ WT1,
                     const float* __restrict__ W2, float* __restrict__ WT2,
                     int* __restrict__ bcursor,
                     int K1, int F1, int KP1, int FP1,
                     int K2, int F2, int KP2, int FP2, int NBZ) {
    int i = blockIdx.x * blockDim.x + threadIdx.x;
    int z1 = FP1 * KP1, z2 = FP2 * KP2;
    if (i < z1) {
        int f = i / KP1, k = i - f * KP1;
        WT1[i] = (f < F1 && k < K1) ? W1[k * F1 + f] : 0.f;
    } else if (i < z1 + z2) {
        int j = i - z1;
        int f = j / KP2, k = j - f * KP2;
        WT2[j] = (f < F2 && k < K2) ? W2[k * F2 + f] : 0.f;
    } else if (i < z1 + z2 + NBZ) {
        bcursor[i - z1 - z2] = 0;     // NB bucket cursors + 2*QPARTS*QSTRIDE queue ints
    }
}

// ---------------- CSR build ----------------

// bin edges into fixed-capacity bucket regions; pack (dst&255)<<17 | src
__global__ __launch_bounds__(512) void binning(
        const int* __restrict__ src, const int* __restrict__ dst,
        int* __restrict__ bcursor, int* __restrict__ binned,
        long E, int N, long TOT) {
    __shared__ int hist[512];
    __shared__ int base[512];
    int t = threadIdx.x;
    hist[t] = 0;
    __syncthreads();
    long c0 = blockIdx.x * (long)CHUNK;
    long c1 = c0 + CHUNK; if (c1 > TOT) c1 = TOT;
    for (long i = c0 + t; i < c1; i += 512) {
        int d = (i < E) ? dst[i] : (int)(i - E);
        atomicAdd(&hist[d >> RBITS], 1);
    }
    __syncthreads();
    {
        int c = hist[t];
        base[t] = c ? atomicAdd(&bcursor[t], c) : 0;
        hist[t] = 0;
    }
    __syncthreads();
    for (long i = c0 + t; i < c1; i += 512) {
        int s, d;
        if (i < E) { s = src[i]; d = dst[i]; } else { s = d = (int)(i - E); }
        int b = d >> RBITS;
        int p = base[b] + atomicAdd(&hist[b], 1);
        if (p >= CAP) p = CAP - 1;   // safety clamp (never hit for this input)
        binned[(long)b * CAP + p] = ((d & (RNODES - 1)) << 17) | s;
    }
}

// single block (512 thr): exclusive scan of bucket counts (bcursor) -> bstarts[0..NB]
__global__ __launch_bounds__(512) void bucket_scan(
        const int* __restrict__ bcursor, int* __restrict__ bstarts,
        int* __restrict__ starts, int NB, int N, int TOT) {
    __shared__ int s[512];
    int t = threadIdx.x;
    int v = (t < NB) ? bcursor[t] : 0;
    s[t] = v;
    __syncthreads();
    for (int off = 1; off < 512; off <<= 1) {
        int u = (t >= off) ? s[t - off] : 0;
        __syncthreads();
        s[t] += u;
        __syncthreads();
    }
    int excl = s[t] - v;
    if (t < NB) bstarts[t] = excl;
    if (t == 0) { bstarts[NB] = TOT; starts[N] = TOT; }
}

// one block (512 thr) per bucket: per-node counts, LDS scan -> starts, compacting scatter
__global__ __launch_bounds__(512) void bucket_csr(
        const int* __restrict__ binned, const int* __restrict__ bstarts,
        int* __restrict__ starts, int* __restrict__ csr_src, int N) {
    __shared__ int cnt[RNODES];
    __shared__ int scn[RNODES];
    int b = blockIdx.x, t = threadIdx.x;
    int node0 = b << RBITS;
    int R = N - node0; if (R > RNODES) R = RNODES;
    int e0 = bstarts[b];
    int ecnt = bstarts[b + 1] - e0;
    const int* bin = binned + (long)b * CAP;
    if (t < RNODES) cnt[t] = 0;
    __syncthreads();
    for (int i = t; i < ecnt; i += 512)
        atomicAdd(&cnt[bin[i] >> 17], 1);
    __syncthreads();
    int v = (t < RNODES) ? cnt[t] : 0;
    if (t < RNODES) scn[t] = v;
    __syncthreads();
    for (int off = 1; off < RNODES; off <<= 1) {
        int u = (t >= off && t < RNODES) ? scn[t - off] : 0;
        __syncthreads();
        if (t < RNODES) scn[t] += u;
        __syncthreads();
    }
    if (t < RNODES) {
        int excl = scn[t] - v;
        if (t < R) starts[node0 + t] = e0 + excl;
        cnt[t] = excl;   // reuse as cursor
    }
    __syncthreads();
    for (int i = t; i < ecnt; i += 512) {
        int packed = bin[i];
        int ld = packed >> 17;
        int p = atomicAdd(&cnt[ld], 1);
        csr_src[e0 + p] = packed & 0x1FFFF;
    }
}

// ---------------- GEMM: lane=node, scalar W, LDS-transposed x ----------------
// block = 512 thr = 8 waves; 64-node tile; wave w computes features 8w..8w+7.
// hb rows zero-padded through uint FPH-1 (acc==0 for f>=F since WT zero-padded).
template <int K, int KP, int F, int FPH>
__global__ __launch_bounds__(512) void gemm_tile(
        const float* __restrict__ x, const float* __restrict__ WT,
        const float* __restrict__ att_s, const float* __restrict__ att_d,
        unsigned* __restrict__ hb, float* __restrict__ as_, float* __restrict__ ad_,
        int N) {
    __shared__ float xT[KP * 65];
    __shared__ float asl[64], adl[64];
    int t = threadIdx.x;
    int lane = t & 63;
    int w = t >> 6;
    long n0 = (long)blockIdx.x * 64;
    int n = (int)n0 + lane;

    if (t < 64) { asl[t] = 0.f; adl[t] = 0.f; }
    for (int idx = t; idx < KP * 64; idx += 512) {
        int nn = idx / KP, k = idx - nn * KP;
        float v = 0.f;
        if (k < K && n0 + nn < N) v = x[(n0 + nn) * (long)K + k];
        xT[k * 65 + nn] = v;
    }
    __syncthreads();

    int f0 = __builtin_amdgcn_readfirstlane(w * 8);
    float acc[8] = {0.f, 0.f, 0.f, 0.f, 0.f, 0.f, 0.f, 0.f};
    if (f0 < F) {
        const float* wbase = WT + (long)f0 * KP;
        for (int k0 = 0; k0 < KP; k0 += 4) {
            float x0 = xT[(k0 + 0) * 65 + lane];
            float x1 = xT[(k0 + 1) * 65 + lane];
            float x2 = xT[(k0 + 2) * 65 + lane];
            float x3 = xT[(k0 + 3) * 65 + lane];
            #pragma unroll
            for (int j = 0; j < 8; ++j) {
                const float* wr = wbase + j * KP + k0;   // wave-uniform -> s_load
                float a = acc[j];
                a = fmaf(wr[0], x0, a);
                a = fmaf(wr[1], x1, a);
                a = fmaf(wr[2], x2, a);
                a = fmaf(wr[3], x3, a);
                acc[j] = a;
            }
        }
        float ps = 0.f, pd = 0.f;
        #pragma unroll
        for (int j = 0; j < 8; ++j) {
            float sa = (f0 + j < F) ? att_s[f0 + j] : 0.f;
            float da = (f0 + j < F) ? att_d[f0 + j] : 0.f;
            ps = fmaf(acc[j], sa, ps);
            pd = fmaf(acc[j], da, pd);
        }
        atomicAdd(&asl[lane], ps);
        atomicAdd(&adl[lane], pd);
    }
    __syncthreads();

    if (f0 < F && n < N) {
        int f0h = f0 >> 1;
        #pragma unroll
        for (int q = 0; q < 4; ++q) {
            int fp = f0h + q;
            if (fp < FPH) hb[(long)n * HS + fp] = pack_bf16(acc[2 * q], acc[2 * q + 1]);
        }
    }
    if (w == 0 && n < N) { as_[n] = asl[lane]; ad_[n] = adl[lane]; }
}

// ---------------- gat gather ----------------
// one wave per dst node; nodes pulled in NBATCH batches from PARTITIONED
// atomic queues (QPARTS counters on separate 128-B lines; block binds to
// partition blockIdx&63). Round-8 lesson: ONE counter line serializes at
// ~16ns/op -> 25K grabs = 400us. Partitioning cuts same-line traffic 64x;
// the next-batch grab is issued BEFORE processing the current batch so the
// atomic latency hides under node work. Eliminates wave-slot stranding from
// degree variance (the persistent ~25% occupancy gap, r0-r7).
// Per-node body is the round-3 form verbatim: phase-A batched w computation
// (r5/r7 lesson), octet uint4 gathers, degree-matched work (r2), no
// min-waves clause (r1), no extra pass (r6).
template <int F>
__global__ __launch_bounds__(256) void gat_gather(
                           const int* __restrict__ csr_src, const int* __restrict__ starts,
                           const float* __restrict__ as_, const float* __restrict__ ad_,
                           const unsigned* __restrict__ hb, const float* __restrict__ bias,
                           float* __restrict__ out, int N, int* __restrict__ qc, int psz) {
    constexpr int NU4 = (F + 7) / 8;        // uint4 per row: 7 (F=50) / 5 (F=40)
    int lane = threadIdx.x & 63;
    int g  = lane >> 3;                     // octet (edge slot) 0..7
    int fl = lane & 7;                      // feature lane
    bool actf = (fl < NU4);
    const unsigned* hbase = hb + 4 * fl;    // lane-fixed feature offset (16B aligned)

    int p = blockIdx.x & (QPARTS - 1);
    int plo = p * psz;
    int phi = plo + psz; if (phi > N) phi = N;
    int* ctr = qc + p * QSTRIDE;

    int cur;
    if (lane == 0) cur = atomicAdd(ctr, 1);
    cur = __shfl(cur, 0);

    for (;;) {
        int nlo = plo + cur * NBATCH;
        if (nlo >= phi) break;
        int nhi = nlo + NBATCH; if (nhi > phi) nhi = phi;
        int nxt;
        if (lane == 0) nxt = atomicAdd(ctr, 1);   // prefetch next batch (hides latency)

        for (int d = nlo; d < nhi; ++d) {
            int s0 = starts[d], s1 = starts[d + 1];
            float add = ad_[d];

            float lsum = 0.f;
            float a0 = 0.f, a1 = 0.f, a2 = 0.f, a3 = 0.f;
            float a4 = 0.f, a5 = 0.f, a6 = 0.f, a7 = 0.f;

            for (int base = s0; base < s1; base += 64) {
                int k = base + lane;
                int s = (k < s1) ? csr_src[k] : 0;    // invalid lanes -> row 0 (w=0)
                unsigned soff = (unsigned)s * HS;     // row offset in uints
                float e = as_[s] + add;
                e = e > 0.f ? e : NEG_SLOPE * e;
                float w = (k < s1) ? __expf(e) : 0.f;
                lsum += w;
                int cnt = min(64, s1 - base);
                int nst = (cnt + 7) >> 3;             // octet steps (1..8)
                int j = 0;
                for (; j + 4 <= nst; j += 4) {
                    int i0 = 8 * j + g;
                    unsigned so0 = __shfl(soff, i0);
                    unsigned so1 = __shfl(soff, i0 + 8);
                    unsigned so2 = __shfl(soff, i0 + 16);
                    unsigned so3 = __shfl(soff, i0 + 24);
                    uint4 h0 = make_uint4(0u,0u,0u,0u), h1 = h0, h2 = h0, h3 = h0;
                    if (actf) {
                        h0 = *(const uint4*)(hbase + so0);
                        h1 = *(const uint4*)(hbase + so1);
                        h2 = *(const uint4*)(hbase + so2);
                        h3 = *(const uint4*)(hbase + so3);
                    }
                    float w0 = __shfl(w, i0);
                    float w1 = __shfl(w, i0 + 8);
                    float w2 = __shfl(w, i0 + 16);
                    float w3 = __shfl(w, i0 + 24);
                    a0 = fmaf(w0, bf16lo_f(h0.x), a0); a1 = fmaf(w0, bf16hi_f(h0.x), a1);
                    a2 = fmaf(w0, bf16lo_f(h0.y), a2); a3 = fmaf(w0, bf16hi_f(h0.y), a3);
                    a4 = fmaf(w0, bf16lo_f(h0.z), a4); a5 = fmaf(w0, bf16hi_f(h0.z), a5);
                    a6 = fmaf(w0, bf16lo_f(h0.w), a6); a7 = fmaf(w0, bf16hi_f(h0.w), a7);
                    a0 = fmaf(w1, bf16lo_f(h1.x), a0); a1 = fmaf(w1, bf16hi_f(h1.x), a1);
                    a2 = fmaf(w1, bf16lo_f(h1.y), a2); a3 = fmaf(w1, bf16hi_f(h1.y), a3);
                    a4 = fmaf(w1, bf16lo_f(h1.z), a4); a5 = fmaf(w1, bf16hi_f(h1.z), a5);
                    a6 = fmaf(w1, bf16lo_f(h1.w), a6); a7 = fmaf(w1, bf16hi_f(h1.w), a7);
                    a0 = fmaf(w2, bf16lo_f(h2.x), a0); a1 = fmaf(w2, bf16hi_f(h2.x), a1);
                    a2 = fmaf(w2, bf16lo_f(h2.y), a2); a3 = fmaf(w2, bf16hi_f(h2.y), a3);
                    a4 = fmaf(w2, bf16lo_f(h2.z), a4); a5 = fmaf(w2, bf16hi_f(h2.z), a5);
                    a6 = fmaf(w2, bf16lo_f(h2.w), a6); a7 = fmaf(w2, bf16hi_f(h2.w), a7);
                    a0 = fmaf(w3, bf16lo_f(h3.x), a0); a1 = fmaf(w3, bf16hi_f(h3.x), a1);
                    a2 = fmaf(w3, bf16lo_f(h3.y), a2); a3 = fmaf(w3, bf16hi_f(h3.y), a3);
                    a4 = fmaf(w3, bf16lo_f(h3.z), a4); a5 = fmaf(w3, bf16hi_f(h3.z), a5);
                    a6 = fmaf(w3, bf16lo_f(h3.w), a6); a7 = fmaf(w3, bf16hi_f(h3.w), a7);
                }
                for (; j < nst; ++j) {
                    int idx = 8 * j + g;
                    float wp = __shfl(w, idx);
                    unsigned so = __shfl(soff, idx);
                    if (actf) {
                        uint4 hv = *(const uint4*)(hbase + so);
                        a0 = fmaf(wp, bf16lo_f(hv.x), a0); a1 = fmaf(wp, bf16hi_f(hv.x), a1);
                        a2 = fmaf(wp, bf16lo_f(hv.y), a2); a3 = fmaf(wp, bf16hi_f(hv.y), a3);
                        a4 = fmaf(wp, bf16lo_f(hv.z), a4); a5 = fmaf(wp, bf16hi_f(hv.z), a5);
                        a6 = fmaf(wp, bf16lo_f(hv.w), a6); a7 = fmaf(wp, bf16hi_f(hv.w), a7);
                    }
                }
            }

            // combine the eight octet partials
            #pragma unroll
            for (int off = 8; off < 64; off <<= 1) {
                a0 += __shfl_xor(a0, off); a1 += __shfl_xor(a1, off);
                a2 += __shfl_xor(a2, off); a3 += __shfl_xor(a3, off);
                a4 += __shfl_xor(a4, off); a5 += __shfl_xor(a5, off);
                a6 += __shfl_xor(a6, off); a7 += __shfl_xor(a7, off);
            }
            float l = waveReduceSum(lsum);

            if (actf && g == 0) {
                float inv = 1.f / l;
                int fb = 8 * fl;
                float v[8] = {a0, a1, a2, a3, a4, a5, a6, a7};
                float2* orow = (float2*)(out + (long)d * F + fb);   // 8B-aligned (F even)
                #pragma unroll
                for (int i = 0; i < 8; i += 2) {
                    if (fb + i < F) {            // F even -> pair fully valid
                        float u0 = v[i]     * inv + bias[fb + i];
                        float u1 = v[i + 1] * inv + bias[fb + i + 1];
                        u0 = u0 > 0.f ? u0 : 0.f;
                        u1 = u1 > 0.f ? u1 : 0.f;
                        orow[i >> 1] = make_float2(u0, u1);
                    }
                }
            }
        }
        nxt = __shfl(nxt, 0);
        cur = nxt;
    }
}

// edge_index passthrough as float (vectorized)
__global__ void copy_edges4(const int4* __restrict__ ei, float4* __restrict__ out, long n4) {
    long i = blockIdx.x * (long)blockDim.x + threadIdx.x;
    if (i < n4) {
        int4 v = ei[i];
        out[i] = make_float4((float)v.x, (float)v.y, (float)v.z, (float)v.w);
    }
}
__global__ void copy_edges_tail(const int* __restrict__ ei, float* __restrict__ out,
                                long lo, long n) {
    long i = lo + blockIdx.x * (long)blockDim.x + threadIdx.x;
    if (i < n) out[i] = (float)ei[i];
}

// ---------------- launch ----------------

extern "C" void kernel_launch(void* const* d_in, const int* in_sizes, int n_in,
                              void* d_out, int out_size, void* d_ws, size_t ws_size,
                              hipStream_t stream) {
    const float* x         = (const float*)d_in[0];
    const int*   edge_idx  = (const int*)d_in[1];
    const float* W1        = (const float*)d_in[2];
    const float* att_src1  = (const float*)d_in[3];
    const float* att_dst1  = (const float*)d_in[4];
    const float* bias1     = (const float*)d_in[5];
    const float* W2        = (const float*)d_in[6];
    const float* att_src2  = (const float*)d_in[7];
    const float* att_dst2  = (const float*)d_in[8];
    const float* bias2     = (const float*)d_in[9];

    const int  CIN = 128, F1 = 50, F2 = 40;
    const int  KP1 = 128, FP1 = 56;            // padded W1T dims
    const int  KP2 = 52,  FP2 = 40;            // padded W2T dims
    const int  N = in_sizes[0] / CIN;          // 100000
    const long E = in_sizes[1] / 2;            // 3200000
    const int* src = edge_idx;
    const int* dst = edge_idx + E;
    const long TOT = E + N;                    // edges incl self-loops
    const int  NB = (N + RNODES - 1) >> RBITS; // 391 buckets (<=512)
    const int  QTOT = 2 * QPARTS * QSTRIDE;    // queue counter region (ints)

    // ---- workspace layout ----
    char* wsb = (char*)d_ws;
    size_t regionA = (size_t)NB * CAP * 4;                        // 14.4 MB
    if ((size_t)N * HS * 4 > regionA) regionA = (size_t)N * HS * 4;
    int*      binned = (int*)wsb;
    unsigned* hb     = (unsigned*)wsb;
    float*    hout   = (float*)(wsb + regionA);         // N*F1 floats (20 MB)
    float*    as_    = hout + (long)N * F1;             // N
    float*    ad_    = as_ + N;                         // N
    int*      starts  = (int*)(ad_ + N);                // N+1
    int*      csr_src = starts + (N + 1);               // TOT
    int*      bstarts = csr_src + TOT;                  // NB+1
    int*      bcursor = bstarts + (NB + 1);             // NB + queue counters
    int*      qc1     = bcursor + NB;                   // QPARTS counters (layer 1)
    int*      qc2     = qc1 + QPARTS * QSTRIDE;         // QPARTS counters (layer 2)
    float*    WT1     = (float*)(qc2 + QPARTS * QSTRIDE); // FP1*KP1
    float*    WT2     = WT1 + FP1 * KP1;                // FP2*KP2

    float* out_h = (float*)d_out;              // N*F2
    float* out_e = out_h + (long)N * F2;       // 2*E

    const int B = 256;
    const int gatBlocks = 2048;                // 8192 waves pulling from 64 queues
    const int psz = (N + QPARTS - 1) / QPARTS; // nodes per partition (1563)
    const int nTileBlocks = (N + 63) / 64;     // gemm: 64-node tiles
    const int nBinBlocks = (int)((TOT + CHUNK - 1) / CHUNK);
    const int prepElems = FP1 * KP1 + FP2 * KP2 + NB + QTOT;

    // ---- prep (WT transposes + cursor/queue zero) + CSR build ----
    prep<<<dim3((prepElems + B - 1) / B), dim3(B), 0, stream>>>(
        W1, WT1, W2, WT2, bcursor, CIN, F1, KP1, FP1, F1, F2, KP2, FP2, NB + QTOT);
    binning<<<dim3(nBinBlocks), dim3(512), 0, stream>>>(src, dst, bcursor, binned, E, N, TOT);
    bucket_scan<<<dim3(1), dim3(512), 0, stream>>>(bcursor, bstarts, starts, NB, N, (int)TOT);
    bucket_csr<<<dim3(NB), dim3(512), 0, stream>>>(binned, bstarts, starts, csr_src, N);

    // ---- layer 1 ----
    gemm_tile<CIN, KP1, F1, FP1 / 2><<<dim3(nTileBlocks), dim3(512), 0, stream>>>(
        x, WT1, att_src1, att_dst1, hb, as_, ad_, N);
    gat_gather<F1><<<dim3(gatBlocks), dim3(B), 0, stream>>>(
        csr_src, starts, as_, ad_, hb, bias1, hout, N, qc1, psz);

    // ---- layer 2 ----
    gemm_tile<F1, KP2, F2, FP2 / 2><<<dim3(nTileBlocks), dim3(512), 0, stream>>>(
        hout, WT2, att_src2, att_dst2, hb, as_, ad_, N);
    gat_gather<F2><<<dim3(gatBlocks), dim3(B), 0, stream>>>(
        csr_src, starts, as_, ad_, hb, bias2, out_h, N, qc2, psz);

    // ---- edge_index passthrough ----
    long n_e = 2 * E;
    long n4  = n_e / 4;
    copy_edges4<<<dim3((int)((n4 + B - 1) / B)), dim3(B), 0, stream>>>((const int4*)edge_idx, (float4*)out_e, n4);
    if (n_e - n4 * 4 > 0)
        copy_edges_tail<<<dim3(1), dim3(B), 0, stream>>>(edge_idx, out_e, n4 * 4, n_e);
}

// Round 10
// 405.088 us; speedup vs baseline: 2.6681x; 1.0368x over previous
//
#include <hip/hip_runtime.h>
#include <hip/hip_bf16.h>
#include <math.h>

#define NEG_SLOPE 0.2f
#define RBITS 8
#define RNODES 256          // nodes per bucket
#define CHUNK 8192          // edges per binning block
#define CAP   9216          // per-bucket region capacity (mean 8440 + ~8 sigma)
#define HS    32            // hb row stride in uints (128 B, line-aligned)

// ---------------- helpers ----------------

__device__ __forceinline__ float waveReduceSum(float v) {
    #pragma unroll
    for (int off = 32; off > 0; off >>= 1) v += __shfl_xor(v, off);
    return v;
}

__device__ __forceinline__ unsigned pack_bf16(float a, float b) {
    __hip_bfloat162 p(__float2bfloat16(a), __float2bfloat16(b));
    return *reinterpret_cast<unsigned*>(&p);
}
__device__ __forceinline__ float bf16lo_f(unsigned u) { return __uint_as_float(u << 16); }
__device__ __forceinline__ float bf16hi_f(unsigned u) { return __uint_as_float(u & 0xFFFF0000u); }

// ---------------- fused prep: WT1, WT2 transpose + bcursor zero ----------------

__global__ void prep(const float* __restrict__ W1, float* __restrict__ WT1,
                     const float* __restrict__ W2, float* __restrict__ WT2,
                     int* __restrict__ bcursor,
                     int K1, int F1, int KP1, int FP1,
                     int K2, int F2, int KP2, int FP2, int NB) {
    int i = blockIdx.x * blockDim.x + threadIdx.x;
    int z1 = FP1 * KP1, z2 = FP2 * KP2;
    if (i < z1) {
        int f = i / KP1, k = i - f * KP1;
        WT1[i] = (f < F1 && k < K1) ? W1[k * F1 + f] : 0.f;
    } else if (i < z1 + z2) {
        int j = i - z1;
        int f = j / KP2, k = j - f * KP2;
        WT2[j] = (f < F2 && k < K2) ? W2[k * F2 + f] : 0.f;
    } else if (i < z1 + z2 + NB) {
        bcursor[i - z1 - z2] = 0;
    }
}

// ---------------- CSR build ----------------

// bin edges into fixed-capacity bucket regions; pack (dst&255)<<17 | src
__global__ __launch_bounds__(512) void binning(
        const int* __restrict__ src, const int* __restrict__ dst,
        int* __restrict__ bcursor, int* __restrict__ binned,
        long E, int N, long TOT) {
    __shared__ int hist[512];
    __shared__ int base[512];
    int t = threadIdx.x;
    hist[t] = 0;
    __syncthreads();
    long c0 = blockIdx.x * (long)CHUNK;
    long c1 = c0 + CHUNK; if (c1 > TOT) c1 = TOT;
    for (long i = c0 + t; i < c1; i += 512) {
        int d = (i < E) ? dst[i] : (int)(i - E);
        atomicAdd(&hist[d >> RBITS], 1);
    }
    __syncthreads();
    {
        int c = hist[t];
        base[t] = c ? atomicAdd(&bcursor[t], c) : 0;
        hist[t] = 0;
    }
    __syncthreads();
    for (long i = c0 + t; i < c1; i += 512) {
        int s, d;
        if (i < E) { s = src[i]; d = dst[i]; } else { s = d = (int)(i - E); }
        int b = d >> RBITS;
        int p = base[b] + atomicAdd(&hist[b], 1);
        if (p >= CAP) p = CAP - 1;   // safety clamp (never hit for this input)
        binned[(long)b * CAP + p] = ((d & (RNODES - 1)) << 17) | s;
    }
}

// single block (512 thr): exclusive scan of bucket counts (bcursor) -> bstarts[0..NB]
__global__ __launch_bounds__(512) void bucket_scan(
        const int* __restrict__ bcursor, int* __restrict__ bstarts,
        int* __restrict__ starts, int NB, int N, int TOT) {
    __shared__ int s[512];
    int t = threadIdx.x;
    int v = (t < NB) ? bcursor[t] : 0;
    s[t] = v;
    __syncthreads();
    for (int off = 1; off < 512; off <<= 1) {
        int u = (t >= off) ? s[t - off] : 0;
        __syncthreads();
        s[t] += u;
        __syncthreads();
    }
    int excl = s[t] - v;
    if (t < NB) bstarts[t] = excl;
    if (t == 0) { bstarts[NB] = TOT; starts[N] = TOT; }
}

// one block (512 thr) per bucket: per-node counts, LDS scan -> starts, compacting scatter
__global__ __launch_bounds__(512) void bucket_csr(
        const int* __restrict__ binned, const int* __restrict__ bstarts,
        int* __restrict__ starts, int* __restrict__ csr_src, int N) {
    __shared__ int cnt[RNODES];
    __shared__ int scn[RNODES];
    int b = blockIdx.x, t = threadIdx.x;
    int node0 = b << RBITS;
    int R = N - node0; if (R > RNODES) R = RNODES;
    int e0 = bstarts[b];
    int ecnt = bstarts[b + 1] - e0;
    const int* bin = binned + (long)b * CAP;
    if (t < RNODES) cnt[t] = 0;
    __syncthreads();
    for (int i = t; i < ecnt; i += 512)
        atomicAdd(&cnt[bin[i] >> 17], 1);
    __syncthreads();
    int v = (t < RNODES) ? cnt[t] : 0;
    if (t < RNODES) scn[t] = v;
    __syncthreads();
    for (int off = 1; off < RNODES; off <<= 1) {
        int u = (t >= off && t < RNODES) ? scn[t - off] : 0;
        __syncthreads();
        if (t < RNODES) scn[t] += u;
        __syncthreads();
    }
    if (t < RNODES) {
        int excl = scn[t] - v;
        if (t < R) starts[node0 + t] = e0 + excl;
        cnt[t] = excl;   // reuse as cursor
    }
    __syncthreads();
    for (int i = t; i < ecnt; i += 512) {
        int packed = bin[i];
        int ld = packed >> 17;
        int p = atomicAdd(&cnt[ld], 1);
        csr_src[e0 + p] = packed & 0x1FFFF;
    }
}

// ---------------- GEMM: lane=node, scalar W, LDS-transposed x ----------------
// block = 512 thr = 8 waves; 64-node tile; wave w computes features 8w..8w+7.
// hb rows zero-padded through uint FPH-1 (acc==0 for f>=F since WT zero-padded).
template <int K, int KP, int F, int FPH>
__global__ __launch_bounds__(512) void gemm_tile(
        const float* __restrict__ x, const float* __restrict__ WT,
        const float* __restrict__ att_s, const float* __restrict__ att_d,
        unsigned* __restrict__ hb, float* __restrict__ as_, float* __restrict__ ad_,
        int N) {
    __shared__ float xT[KP * 65];
    __shared__ float asl[64], adl[64];
    int t = threadIdx.x;
    int lane = t & 63;
    int w = t >> 6;
    long n0 = (long)blockIdx.x * 64;
    int n = (int)n0 + lane;

    if (t < 64) { asl[t] = 0.f; adl[t] = 0.f; }
    for (int idx = t; idx < KP * 64; idx += 512) {
        int nn = idx / KP, k = idx - nn * KP;
        float v = 0.f;
        if (k < K && n0 + nn < N) v = x[(n0 + nn) * (long)K + k];
        xT[k * 65 + nn] = v;
    }
    __syncthreads();

    int f0 = __builtin_amdgcn_readfirstlane(w * 8);
    float acc[8] = {0.f, 0.f, 0.f, 0.f, 0.f, 0.f, 0.f, 0.f};
    if (f0 < F) {
        const float* wbase = WT + (long)f0 * KP;
        for (int k0 = 0; k0 < KP; k0 += 4) {
            float x0 = xT[(k0 + 0) * 65 + lane];
            float x1 = xT[(k0 + 1) * 65 + lane];
            float x2 = xT[(k0 + 2) * 65 + lane];
            float x3 = xT[(k0 + 3) * 65 + lane];
            #pragma unroll
            for (int j = 0; j < 8; ++j) {
                const float* wr = wbase + j * KP + k0;   // wave-uniform -> s_load
                float a = acc[j];
                a = fmaf(wr[0], x0, a);
                a = fmaf(wr[1], x1, a);
                a = fmaf(wr[2], x2, a);
                a = fmaf(wr[3], x3, a);
                acc[j] = a;
            }
        }
        float ps = 0.f, pd = 0.f;
        #pragma unroll
        for (int j = 0; j < 8; ++j) {
            float sa = (f0 + j < F) ? att_s[f0 + j] : 0.f;
            float da = (f0 + j < F) ? att_d[f0 + j] : 0.f;
            ps = fmaf(acc[j], sa, ps);
            pd = fmaf(acc[j], da, pd);
        }
        atomicAdd(&asl[lane], ps);
        atomicAdd(&adl[lane], pd);
    }
    __syncthreads();

    if (f0 < F && n < N) {
        int f0h = f0 >> 1;
        #pragma unroll
        for (int q = 0; q < 4; ++q) {
            int fp = f0h + q;
            if (fp < FPH) hb[(long)n * HS + fp] = pack_bf16(acc[2 * q], acc[2 * q + 1]);
        }
    }
    if (w == 0 && n < N) { as_[n] = asl[lane]; ad_[n] = adl[lane]; }
}

// ---------------- gat gather ----------------
// one wave per dst node: single-pass softmax (|e| small; exp safe).
// OCTET layout: 8 lanes per edge (group g = lane>>3), lane fl = lane&7 loads
// uint4 (8 bf16 features). Round-3 body verbatim (best verified: 406.5 us).
// Launched as ONE WAVE PER BLOCK (<<<N,64>>>): no intra-block wave-slot
// stranding from degree variance -- the HW scheduler backfills each retired
// slot immediately. Zero-overhead test of the stranding hypothesis (r8/r9
// queue variants confounded it with atomic/binding overheads).
// Degree-matched work (r2 lesson); no min-waves clause (r1 spill lesson);
// phase-A batched w computation overlapping gathers (r5/r7 lesson); no
// extra edge pass (r6 lesson).
template <int F>
__global__ __launch_bounds__(64) void gat_gather(
                           const int* __restrict__ csr_src, const int* __restrict__ starts,
                           const float* __restrict__ as_, const float* __restrict__ ad_,
                           const unsigned* __restrict__ hb, const float* __restrict__ bias,
                           float* __restrict__ out, int N) {
    constexpr int NU4 = (F + 7) / 8;        // uint4 per row: 7 (F=50) / 5 (F=40)
    int lane = threadIdx.x & 63;
    int g  = lane >> 3;                     // octet (edge slot) 0..7
    int fl = lane & 7;                      // feature lane
    bool actf = (fl < NU4);
    long wave = (blockIdx.x * (long)blockDim.x + threadIdx.x) >> 6;
    if (wave >= N) return;
    int d = (int)wave;
    int s0 = starts[d], s1 = starts[d + 1];
    float add = ad_[d];
    const unsigned* hbase = hb + 4 * fl;    // lane-fixed feature offset (16B aligned)

    float lsum = 0.f;
    float a0 = 0.f, a1 = 0.f, a2 = 0.f, a3 = 0.f;
    float a4 = 0.f, a5 = 0.f, a6 = 0.f, a7 = 0.f;

    for (int base = s0; base < s1; base += 64) {
        int k = base + lane;
        int s = (k < s1) ? csr_src[k] : 0;        // invalid lanes -> row 0 (w=0 later)
        unsigned soff = (unsigned)s << 5;         // row offset in uints (HS=32)
        float e = as_[s] + add;
        e = e > 0.f ? e : NEG_SLOPE * e;
        float w = (k < s1) ? __expf(e) : 0.f;
        lsum += w;
        int cnt = min(64, s1 - base);
        int nst = (cnt + 7) >> 3;                 // octet steps (1..8)
        int j = 0;
        for (; j + 4 <= nst; j += 4) {
            int i0 = 8 * j + g;
            unsigned so0 = __shfl(soff, i0);
            unsigned so1 = __shfl(soff, i0 + 8);
            unsigned so2 = __shfl(soff, i0 + 16);
            unsigned so3 = __shfl(soff, i0 + 24);
            uint4 h0 = make_uint4(0u,0u,0u,0u), h1 = h0, h2 = h0, h3 = h0;
            if (actf) {
                h0 = *(const uint4*)(hbase + so0);
                h1 = *(const uint4*)(hbase + so1);
                h2 = *(const uint4*)(hbase + so2);
                h3 = *(const uint4*)(hbase + so3);
            }
            float w0 = __shfl(w, i0);
            float w1 = __shfl(w, i0 + 8);
            float w2 = __shfl(w, i0 + 16);
            float w3 = __shfl(w, i0 + 24);
            a0 = fmaf(w0, bf16lo_f(h0.x), a0); a1 = fmaf(w0, bf16hi_f(h0.x), a1);
            a2 = fmaf(w0, bf16lo_f(h0.y), a2); a3 = fmaf(w0, bf16hi_f(h0.y), a3);
            a4 = fmaf(w0, bf16lo_f(h0.z), a4); a5 = fmaf(w0, bf16hi_f(h0.z), a5);
            a6 = fmaf(w0, bf16lo_f(h0.w), a6); a7 = fmaf(w0, bf16hi_f(h0.w), a7);
            a0 = fmaf(w1, bf16lo_f(h1.x), a0); a1 = fmaf(w1, bf16hi_f(h1.x), a1);
            a2 = fmaf(w1, bf16lo_f(h1.y), a2); a3 = fmaf(w1, bf16hi_f(h1.y), a3);
            a4 = fmaf(w1, bf16lo_f(h1.z), a4); a5 = fmaf(w1, bf16hi_f(h1.z), a5);
            a6 = fmaf(w1, bf16lo_f(h1.w), a6); a7 = fmaf(w1, bf16hi_f(h1.w), a7);
            a0 = fmaf(w2, bf16lo_f(h2.x), a0); a1 = fmaf(w2, bf16hi_f(h2.x), a1);
            a2 = fmaf(w2, bf16lo_f(h2.y), a2); a3 = fmaf(w2, bf16hi_f(h2.y), a3);
            a4 = fmaf(w2, bf16lo_f(h2.z), a4); a5 = fmaf(w2, bf16hi_f(h2.z), a5);
            a6 = fmaf(w2, bf16lo_f(h2.w), a6); a7 = fmaf(w2, bf16hi_f(h2.w), a7);
            a0 = fmaf(w3, bf16lo_f(h3.x), a0); a1 = fmaf(w3, bf16hi_f(h3.x), a1);
            a2 = fmaf(w3, bf16lo_f(h3.y), a2); a3 = fmaf(w3, bf16hi_f(h3.y), a3);
            a4 = fmaf(w3, bf16lo_f(h3.z), a4); a5 = fmaf(w3, bf16hi_f(h3.z), a5);
            a6 = fmaf(w3, bf16lo_f(h3.w), a6); a7 = fmaf(w3, bf16hi_f(h3.w), a7);
        }
        for (; j < nst; ++j) {
            int idx = 8 * j + g;
            float wp = __shfl(w, idx);
            unsigned so = __shfl(soff, idx);
            if (actf) {
                uint4 hv = *(const uint4*)(hbase + so);
                a0 = fmaf(wp, bf16lo_f(hv.x), a0); a1 = fmaf(wp, bf16hi_f(hv.x), a1);
                a2 = fmaf(wp, bf16lo_f(hv.y), a2); a3 = fmaf(wp, bf16hi_f(hv.y), a3);
                a4 = fmaf(wp, bf16lo_f(hv.z), a4); a5 = fmaf(wp, bf16hi_f(hv.z), a5);
                a6 = fmaf(wp, bf16lo_f(hv.w), a6); a7 = fmaf(wp, bf16hi_f(hv.w), a7);
            }
        }
    }

    // combine the eight octet partials (feature f = 8*fl + i lives in all groups)
    #pragma unroll
    for (int off = 8; off < 64; off <<= 1) {
        a0 += __shfl_xor(a0, off); a1 += __shfl_xor(a1, off);
        a2 += __shfl_xor(a2, off); a3 += __shfl_xor(a3, off);
        a4 += __shfl_xor(a4, off); a5 += __shfl_xor(a5, off);
        a6 += __shfl_xor(a6, off); a7 += __shfl_xor(a7, off);
    }
    float l = waveReduceSum(lsum);

    if (actf) {
        float inv = 1.f / l;
        int fb = 8 * fl;
        float v[8] = {a0, a1, a2, a3, a4, a5, a6, a7};
        float2* orow = (float2*)(out + (long)d * F + fb);   // 8B-aligned (F even)
        #pragma unroll
        for (int i = 0; i < 8; i += 2) {
            if (fb + i < F) {            // F even -> pair fully valid
                float u0 = v[i]     * inv + bias[fb + i];
                float u1 = v[i + 1] * inv + bias[fb + i + 1];
                u0 = u0 > 0.f ? u0 : 0.f;
                u1 = u1 > 0.f ? u1 : 0.f;
                orow[i >> 1] = make_float2(u0, u1);
            }
        }
    }
}

// edge_index passthrough as float (vectorized)
__global__ void copy_edges4(const int4* __restrict__ ei, float4* __restrict__ out, long n4) {
    long i = blockIdx.x * (long)blockDim.x + threadIdx.x;
    if (i < n4) {
        int4 v = ei[i];
        out[i] = make_float4((float)v.x, (float)v.y, (float)v.z, (float)v.w);
    }
}
__global__ void copy_edges_tail(const int* __restrict__ ei, float* __restrict__ out,
                                long lo, long n) {
    long i = lo + blockIdx.x * (long)blockDim.x + threadIdx.x;
    if (i < n) out[i] = (float)ei[i];
}

// ---------------- launch ----------------

extern "C" void kernel_launch(void* const* d_in, const int* in_sizes, int n_in,
                              void* d_out, int out_size, void* d_ws, size_t ws_size,
                              hipStream_t stream) {
    const float* x         = (const float*)d_in[0];
    const int*   edge_idx  = (const int*)d_in[1];
    const float* W1        = (const float*)d_in[2];
    const float* att_src1  = (const float*)d_in[3];
    const float* att_dst1  = (const float*)d_in[4];
    const float* bias1     = (const float*)d_in[5];
    const float* W2        = (const float*)d_in[6];
    const float* att_src2  = (const float*)d_in[7];
    const float* att_dst2  = (const float*)d_in[8];
    const float* bias2     = (const float*)d_in[9];

    const int  CIN = 128, F1 = 50, F2 = 40;
    const int  KP1 = 128, FP1 = 56;            // padded W1T dims
    const int  KP2 = 52,  FP2 = 40;            // padded W2T dims
    const int  N = in_sizes[0] / CIN;          // 100000
    const long E = in_sizes[1] / 2;            // 3200000
    const int* src = edge_idx;
    const int* dst = edge_idx + E;
    const long TOT = E + N;                    // edges incl self-loops
    const int  NB = (N + RNODES - 1) >> RBITS; // 391 buckets (<=512)

    // ---- workspace layout ----
    char* wsb = (char*)d_ws;
    size_t regionA = (size_t)NB * CAP * 4;                        // 14.4 MB
    if ((size_t)N * HS * 4 > regionA) regionA = (size_t)N * HS * 4;
    int*      binned = (int*)wsb;
    unsigned* hb     = (unsigned*)wsb;
    float*    hout   = (float*)(wsb + regionA);         // N*F1 floats (20 MB)
    float*    as_    = hout + (long)N * F1;             // N
    float*    ad_    = as_ + N;                         // N
    int*      starts  = (int*)(ad_ + N);                // N+1
    int*      csr_src = starts + (N + 1);               // TOT
    int*      bstarts = csr_src + TOT;                  // NB+1
    int*      bcursor = bstarts + (NB + 1);             // NB
    float*    WT1     = (float*)(bcursor + NB + 3);     // FP1*KP1
    float*    WT2     = WT1 + FP1 * KP1;                // FP2*KP2

    float* out_h = (float*)d_out;              // N*F2
    float* out_e = out_h + (long)N * F2;       // 2*E

    const int B = 256;
    const int nTileBlocks = (N + 63) / 64;     // gemm: 64-node tiles
    const int nBinBlocks = (int)((TOT + CHUNK - 1) / CHUNK);
    const int prepElems = FP1 * KP1 + FP2 * KP2 + NB;

    // ---- prep (WT transposes + cursor zero) + CSR build ----
    prep<<<dim3((prepElems + B - 1) / B), dim3(B), 0, stream>>>(
        W1, WT1, W2, WT2, bcursor, CIN, F1, KP1, FP1, F1, F2, KP2, FP2, NB);
    binning<<<dim3(nBinBlocks), dim3(512), 0, stream>>>(src, dst, bcursor, binned, E, N, TOT);
    bucket_scan<<<dim3(1), dim3(512), 0, stream>>>(bcursor, bstarts, starts, NB, N, (int)TOT);
    bucket_csr<<<dim3(NB), dim3(512), 0, stream>>>(binned, bstarts, starts, csr_src, N);

    // ---- layer 1 ----
    gemm_tile<CIN, KP1, F1, FP1 / 2><<<dim3(nTileBlocks), dim3(512), 0, stream>>>(
        x, WT1, att_src1, att_dst1, hb, as_, ad_, N);
    gat_gather<F1><<<dim3(N), dim3(64), 0, stream>>>(
        csr_src, starts, as_, ad_, hb, bias1, hout, N);

    // ---- layer 2 ----
    gemm_tile<F1, KP2, F2, FP2 / 2><<<dim3(nTileBlocks), dim3(512), 0, stream>>>(
        hout, WT2, att_src2, att_dst2, hb, as_, ad_, N);
    gat_gather<F2><<<dim3(N), dim3(64), 0, stream>>>(
        csr_src, starts, as_, ad_, hb, bias2, out_h, N);

    // ---- edge_index passthrough ----
    long n_e = 2 * E;
    long n4  = n_e / 4;
    copy_edges4<<<dim3((int)((n4 + B - 1) / B)), dim3(B), 0, stream>>>((const int4*)edge_idx, (float4*)out_e, n4);
    if (n_e - n4 * 4 > 0)
        copy_edges_tail<<<dim3(1), dim3(B), 0, stream>>>(edge_idx, out_e, n4 * 4, n_e);
}

// Round 11
// 391.994 us; speedup vs baseline: 2.7573x; 1.0334x over previous
//
#include <hip/hip_runtime.h>
#include <hip/hip_bf16.h>
#include <math.h>

#define NEG_SLOPE 0.2f
#define RBITS 8
#define RNODES 256          // nodes per bucket
#define CHUNK 8192          // edges per binning block
#define CAP   9216          // per-bucket region capacity (mean 8440 + ~8 sigma)
#define HS    32            // hb row stride in uints (128 B, line-aligned)
#define HOS   56            // hout row stride in floats (224 B, 16B-aligned for vec4)

// ---------------- helpers ----------------

__device__ __forceinline__ float waveReduceSum(float v) {
    #pragma unroll
    for (int off = 32; off > 0; off >>= 1) v += __shfl_xor(v, off);
    return v;
}

__device__ __forceinline__ unsigned pack_bf16(float a, float b) {
    __hip_bfloat162 p(__float2bfloat16(a), __float2bfloat16(b));
    return *reinterpret_cast<unsigned*>(&p);
}
__device__ __forceinline__ float bf16lo_f(unsigned u) { return __uint_as_float(u << 16); }
__device__ __forceinline__ float bf16hi_f(unsigned u) { return __uint_as_float(u & 0xFFFF0000u); }

// ---------------- fused prep: WT1, WT2 transpose + bcursor zero ----------------

__global__ void prep(const float* __restrict__ W1, float* __restrict__ WT1,
                     const float* __restrict__ W2, float* __restrict__ WT2,
                     int* __restrict__ bcursor,
                     int K1, int F1, int KP1, int FP1,
                     int K2, int F2, int KP2, int FP2, int NB) {
    int i = blockIdx.x * blockDim.x + threadIdx.x;
    int z1 = FP1 * KP1, z2 = FP2 * KP2;
    if (i < z1) {
        int f = i / KP1, k = i - f * KP1;
        WT1[i] = (f < F1 && k < K1) ? W1[k * F1 + f] : 0.f;
    } else if (i < z1 + z2) {
        int j = i - z1;
        int f = j / KP2, k = j - f * KP2;
        WT2[j] = (f < F2 && k < K2) ? W2[k * F2 + f] : 0.f;
    } else if (i < z1 + z2 + NB) {
        bcursor[i - z1 - z2] = 0;
    }
}

// ---------------- CSR build ----------------

// bin edges into fixed-capacity bucket regions; pack (dst&255)<<17 | src
__global__ __launch_bounds__(512) void binning(
        const int* __restrict__ src, const int* __restrict__ dst,
        int* __restrict__ bcursor, int* __restrict__ binned,
        long E, int N, long TOT) {
    __shared__ int hist[512];
    __shared__ int base[512];
    int t = threadIdx.x;
    hist[t] = 0;
    __syncthreads();
    long c0 = blockIdx.x * (long)CHUNK;
    long c1 = c0 + CHUNK; if (c1 > TOT) c1 = TOT;
    for (long i = c0 + t; i < c1; i += 512) {
        int d = (i < E) ? dst[i] : (int)(i - E);
        atomicAdd(&hist[d >> RBITS], 1);
    }
    __syncthreads();
    {
        int c = hist[t];
        base[t] = c ? atomicAdd(&bcursor[t], c) : 0;
        hist[t] = 0;
    }
    __syncthreads();
    for (long i = c0 + t; i < c1; i += 512) {
        int s, d;
        if (i < E) { s = src[i]; d = dst[i]; } else { s = d = (int)(i - E); }
        int b = d >> RBITS;
        int p = base[b] + atomicAdd(&hist[b], 1);
        if (p >= CAP) p = CAP - 1;   // safety clamp (never hit for this input)
        binned[(long)b * CAP + p] = ((d & (RNODES - 1)) << 17) | s;
    }
}

// single block (512 thr): exclusive scan of bucket counts (bcursor) -> bstarts[0..NB]
__global__ __launch_bounds__(512) void bucket_scan(
        const int* __restrict__ bcursor, int* __restrict__ bstarts,
        int* __restrict__ starts, int NB, int N, int TOT) {
    __shared__ int s[512];
    int t = threadIdx.x;
    int v = (t < NB) ? bcursor[t] : 0;
    s[t] = v;
    __syncthreads();
    for (int off = 1; off < 512; off <<= 1) {
        int u = (t >= off) ? s[t - off] : 0;
        __syncthreads();
        s[t] += u;
        __syncthreads();
    }
    int excl = s[t] - v;
    if (t < NB) bstarts[t] = excl;
    if (t == 0) { bstarts[NB] = TOT; starts[N] = TOT; }
}

// one block (512 thr) per bucket: per-node counts, LDS scan -> starts, compacting scatter
__global__ __launch_bounds__(512) void bucket_csr(
        const int* __restrict__ binned, const int* __restrict__ bstarts,
        int* __restrict__ starts, int* __restrict__ csr_src, int N) {
    __shared__ int cnt[RNODES];
    __shared__ int scn[RNODES];
    int b = blockIdx.x, t = threadIdx.x;
    int node0 = b << RBITS;
    int R = N - node0; if (R > RNODES) R = RNODES;
    int e0 = bstarts[b];
    int ecnt = bstarts[b + 1] - e0;
    const int* bin = binned + (long)b * CAP;
    if (t < RNODES) cnt[t] = 0;
    __syncthreads();
    for (int i = t; i < ecnt; i += 512)
        atomicAdd(&cnt[bin[i] >> 17], 1);
    __syncthreads();
    int v = (t < RNODES) ? cnt[t] : 0;
    if (t < RNODES) scn[t] = v;
    __syncthreads();
    for (int off = 1; off < RNODES; off <<= 1) {
        int u = (t >= off && t < RNODES) ? scn[t - off] : 0;
        __syncthreads();
        if (t < RNODES) scn[t] += u;
        __syncthreads();
    }
    if (t < RNODES) {
        int excl = scn[t] - v;
        if (t < R) starts[node0 + t] = e0 + excl;
        cnt[t] = excl;   // reuse as cursor
    }
    __syncthreads();
    for (int i = t; i < ecnt; i += 512) {
        int packed = bin[i];
        int ld = packed >> 17;
        int p = atomicAdd(&cnt[ld], 1);
        csr_src[e0 + p] = packed & 0x1FFFF;
    }
}

// ---------------- GEMM: lane=node, scalar W, LDS-transposed x ----------------
// block = 512 thr = 8 waves; 64-node tile; wave w computes features 8w..8w+7.
// hb rows zero-padded through uint FPH-1 (acc==0 for f>=F since WT zero-padded).
// Staging VECTORIZED (r11): float4 x-loads (4x fewer instrs + addr math; r4
// counters showed VALUBusy 19% -> staging-bound, not FMA-bound). Requires
// 16B-aligned rows: XS=128 (input x) / XS=HOS=56 (hout, padded + zero-filled
// by gat1 so pad*0-padded-WT contributes 0). xT stride 66: staging writes
// 4-way bank conflict (vs 8-way at 65), main-loop reads lane-stride-1 clean.
template <int KP, int F, int FPH, int XS>
__global__ __launch_bounds__(512) void gemm_tile(
        const float* __restrict__ x, const float* __restrict__ WT,
        const float* __restrict__ att_s, const float* __restrict__ att_d,
        unsigned* __restrict__ hb, float* __restrict__ as_, float* __restrict__ ad_,
        int N) {
    static_assert(KP % 4 == 0 && XS % 4 == 0 && XS >= KP, "vec4 staging");
    constexpr int Q4 = KP / 4;
    __shared__ float xT[KP * 66];
    __shared__ float asl[64], adl[64];
    int t = threadIdx.x;
    int lane = t & 63;
    int w = t >> 6;
    long n0 = (long)blockIdx.x * 64;
    int n = (int)n0 + lane;

    if (t < 64) { asl[t] = 0.f; adl[t] = 0.f; }
    for (int idx = t; idx < Q4 * 64; idx += 512) {
        int nn = idx / Q4;
        int k4 = (idx - nn * Q4) * 4;
        float4 v = make_float4(0.f, 0.f, 0.f, 0.f);
        if (n0 + nn < N) v = *(const float4*)(x + (n0 + nn) * (long)XS + k4);
        xT[(k4 + 0) * 66 + nn] = v.x;
        xT[(k4 + 1) * 66 + nn] = v.y;
        xT[(k4 + 2) * 66 + nn] = v.z;
        xT[(k4 + 3) * 66 + nn] = v.w;
    }
    __syncthreads();

    int f0 = __builtin_amdgcn_readfirstlane(w * 8);
    float acc[8] = {0.f, 0.f, 0.f, 0.f, 0.f, 0.f, 0.f, 0.f};
    if (f0 < F) {
        const float* wbase = WT + (long)f0 * KP;
        for (int k0 = 0; k0 < KP; k0 += 4) {
            float x0 = xT[(k0 + 0) * 66 + lane];
            float x1 = xT[(k0 + 1) * 66 + lane];
            float x2 = xT[(k0 + 2) * 66 + lane];
            float x3 = xT[(k0 + 3) * 66 + lane];
            #pragma unroll
            for (int j = 0; j < 8; ++j) {
                const float* wr = wbase + j * KP + k0;   // wave-uniform -> s_load
                float a = acc[j];
                a = fmaf(wr[0], x0, a);
                a = fmaf(wr[1], x1, a);
                a = fmaf(wr[2], x2, a);
                a = fmaf(wr[3], x3, a);
                acc[j] = a;
            }
        }
        float ps = 0.f, pd = 0.f;
        #pragma unroll
        for (int j = 0; j < 8; ++j) {
            float sa = (f0 + j < F) ? att_s[f0 + j] : 0.f;
            float da = (f0 + j < F) ? att_d[f0 + j] : 0.f;
            ps = fmaf(acc[j], sa, ps);
            pd = fmaf(acc[j], da, pd);
        }
        atomicAdd(&asl[lane], ps);
        atomicAdd(&adl[lane], pd);
    }
    __syncthreads();

    if (f0 < F && n < N) {
        int f0h = f0 >> 1;
        #pragma unroll
        for (int q = 0; q < 4; ++q) {
            int fp = f0h + q;
            if (fp < FPH) hb[(long)n * HS + fp] = pack_bf16(acc[2 * q], acc[2 * q + 1]);
        }
    }
    if (w == 0 && n < N) { as_[n] = asl[lane]; ad_[n] = adl[lane]; }
}

// ---------------- gat gather ----------------
// one wave per dst node: single-pass softmax (|e| small; exp safe).
// OCTET layout: 8 lanes per edge (group g = lane>>3), lane fl = lane&7 loads
// uint4 (8 bf16 features). Round-10 body (best verified: 405.1 us): 1-wave
// blocks <<<N,64>>> (no degree-variance slot stranding); degree-matched work
// (r2 lesson); no min-waves clause (r1 spill lesson); phase-A batched w
// computation overlapping gathers (r5/r7 lesson); no extra pass (r6 lesson).
// OST (r11): output row stride; OST>F pads written ZERO (hout stride 56 so
// gemm2 can vec4-stage; pad rides the row's own cache lines - free).
template <int F, int OST>
__global__ __launch_bounds__(64) void gat_gather(
                           const int* __restrict__ csr_src, const int* __restrict__ starts,
                           const float* __restrict__ as_, const float* __restrict__ ad_,
                           const unsigned* __restrict__ hb, const float* __restrict__ bias,
                           float* __restrict__ out, int N) {
    constexpr int NU4 = (F + 7) / 8;        // uint4 per row: 7 (F=50) / 5 (F=40)
    int lane = threadIdx.x & 63;
    int g  = lane >> 3;                     // octet (edge slot) 0..7
    int fl = lane & 7;                      // feature lane
    bool actf = (fl < NU4);
    long wave = (blockIdx.x * (long)blockDim.x + threadIdx.x) >> 6;
    if (wave >= N) return;
    int d = (int)wave;
    int s0 = starts[d], s1 = starts[d + 1];
    float add = ad_[d];
    const unsigned* hbase = hb + 4 * fl;    // lane-fixed feature offset (16B aligned)

    float lsum = 0.f;
    float a0 = 0.f, a1 = 0.f, a2 = 0.f, a3 = 0.f;
    float a4 = 0.f, a5 = 0.f, a6 = 0.f, a7 = 0.f;

    for (int base = s0; base < s1; base += 64) {
        int k = base + lane;
        int s = (k < s1) ? csr_src[k] : 0;        // invalid lanes -> row 0 (w=0 later)
        unsigned soff = (unsigned)s << 5;         // row offset in uints (HS=32)
        float e = as_[s] + add;
        e = e > 0.f ? e : NEG_SLOPE * e;
        float w = (k < s1) ? __expf(e) : 0.f;
        lsum += w;
        int cnt = min(64, s1 - base);
        int nst = (cnt + 7) >> 3;                 // octet steps (1..8)
        int j = 0;
        for (; j + 4 <= nst; j += 4) {
            int i0 = 8 * j + g;
            unsigned so0 = __shfl(soff, i0);
            unsigned so1 = __shfl(soff, i0 + 8);
            unsigned so2 = __shfl(soff, i0 + 16);
            unsigned so3 = __shfl(soff, i0 + 24);
            uint4 h0 = make_uint4(0u,0u,0u,0u), h1 = h0, h2 = h0, h3 = h0;
            if (actf) {
                h0 = *(const uint4*)(hbase + so0);
                h1 = *(const uint4*)(hbase + so1);
                h2 = *(const uint4*)(hbase + so2);
                h3 = *(const uint4*)(hbase + so3);
            }
            float w0 = __shfl(w, i0);
            float w1 = __shfl(w, i0 + 8);
            float w2 = __shfl(w, i0 + 16);
            float w3 = __shfl(w, i0 + 24);
            a0 = fmaf(w0, bf16lo_f(h0.x), a0); a1 = fmaf(w0, bf16hi_f(h0.x), a1);
            a2 = fmaf(w0, bf16lo_f(h0.y), a2); a3 = fmaf(w0, bf16hi_f(h0.y), a3);
            a4 = fmaf(w0, bf16lo_f(h0.z), a4); a5 = fmaf(w0, bf16hi_f(h0.z), a5);
            a6 = fmaf(w0, bf16lo_f(h0.w), a6); a7 = fmaf(w0, bf16hi_f(h0.w), a7);
            a0 = fmaf(w1, bf16lo_f(h1.x), a0); a1 = fmaf(w1, bf16hi_f(h1.x), a1);
            a2 = fmaf(w1, bf16lo_f(h1.y), a2); a3 = fmaf(w1, bf16hi_f(h1.y), a3);
            a4 = fmaf(w1, bf16lo_f(h1.z), a4); a5 = fmaf(w1, bf16hi_f(h1.z), a5);
            a6 = fmaf(w1, bf16lo_f(h1.w), a6); a7 = fmaf(w1, bf16hi_f(h1.w), a7);
            a0 = fmaf(w2, bf16lo_f(h2.x), a0); a1 = fmaf(w2, bf16hi_f(h2.x), a1);
            a2 = fmaf(w2, bf16lo_f(h2.y), a2); a3 = fmaf(w2, bf16hi_f(h2.y), a3);
            a4 = fmaf(w2, bf16lo_f(h2.z), a4); a5 = fmaf(w2, bf16hi_f(h2.z), a5);
            a6 = fmaf(w2, bf16lo_f(h2.w), a6); a7 = fmaf(w2, bf16hi_f(h2.w), a7);
            a0 = fmaf(w3, bf16lo_f(h3.x), a0); a1 = fmaf(w3, bf16hi_f(h3.x), a1);
            a2 = fmaf(w3, bf16lo_f(h3.y), a2); a3 = fmaf(w3, bf16hi_f(h3.y), a3);
            a4 = fmaf(w3, bf16lo_f(h3.z), a4); a5 = fmaf(w3, bf16hi_f(h3.z), a5);
            a6 = fmaf(w3, bf16lo_f(h3.w), a6); a7 = fmaf(w3, bf16hi_f(h3.w), a7);
        }
        for (; j < nst; ++j) {
            int idx = 8 * j + g;
            float wp = __shfl(w, idx);
            unsigned so = __shfl(soff, idx);
            if (actf) {
                uint4 hv = *(const uint4*)(hbase + so);
                a0 = fmaf(wp, bf16lo_f(hv.x), a0); a1 = fmaf(wp, bf16hi_f(hv.x), a1);
                a2 = fmaf(wp, bf16lo_f(hv.y), a2); a3 = fmaf(wp, bf16hi_f(hv.y), a3);
                a4 = fmaf(wp, bf16lo_f(hv.z), a4); a5 = fmaf(wp, bf16hi_f(hv.z), a5);
                a6 = fmaf(wp, bf16lo_f(hv.w), a6); a7 = fmaf(wp, bf16hi_f(hv.w), a7);
            }
        }
    }

    // combine the eight octet partials (feature f = 8*fl + i lives in all groups)
    #pragma unroll
    for (int off = 8; off < 64; off <<= 1) {
        a0 += __shfl_xor(a0, off); a1 += __shfl_xor(a1, off);
        a2 += __shfl_xor(a2, off); a3 += __shfl_xor(a3, off);
        a4 += __shfl_xor(a4, off); a5 += __shfl_xor(a5, off);
        a6 += __shfl_xor(a6, off); a7 += __shfl_xor(a7, off);
    }
    float l = waveReduceSum(lsum);

    if (actf) {
        float inv = 1.f / l;
        int fb = 8 * fl;
        float v[8] = {a0, a1, a2, a3, a4, a5, a6, a7};
        float2* orow = (float2*)(out + (long)d * OST + fb);   // 8B-aligned (OST even)
        #pragma unroll
        for (int i = 0; i < 8; i += 2) {
            if (fb + i < OST) {
                float u0 = 0.f, u1 = 0.f;
                if (fb + i < F) {            // F even -> pair fully valid
                    u0 = v[i]     * inv + bias[fb + i];
                    u1 = v[i + 1] * inv + bias[fb + i + 1];
                    u0 = u0 > 0.f ? u0 : 0.f;
                    u1 = u1 > 0.f ? u1 : 0.f;
                }
                orow[i >> 1] = make_float2(u0, u1);   // pads -> 0 (gemm2 vec4 safety)
            }
        }
    }
}

// edge_index passthrough as float (vectorized)
__global__ void copy_edges4(const int4* __restrict__ ei, float4* __restrict__ out, long n4) {
    long i = blockIdx.x * (long)blockDim.x + threadIdx.x;
    if (i < n4) {
        int4 v = ei[i];
        out[i] = make_float4((float)v.x, (float)v.y, (float)v.z, (float)v.w);
    }
}
__global__ void copy_edges_tail(const int* __restrict__ ei, float* __restrict__ out,
                                long lo, long n) {
    long i = lo + blockIdx.x * (long)blockDim.x + threadIdx.x;
    if (i < n) out[i] = (float)ei[i];
}

// ---------------- launch ----------------

extern "C" void kernel_launch(void* const* d_in, const int* in_sizes, int n_in,
                              void* d_out, int out_size, void* d_ws, size_t ws_size,
                              hipStream_t stream) {
    const float* x         = (const float*)d_in[0];
    const int*   edge_idx  = (const int*)d_in[1];
    const float* W1        = (const float*)d_in[2];
    const float* att_src1  = (const float*)d_in[3];
    const float* att_dst1  = (const float*)d_in[4];
    const float* bias1     = (const float*)d_in[5];
    const float* W2        = (const float*)d_in[6];
    const float* att_src2  = (const float*)d_in[7];
    const float* att_dst2  = (const float*)d_in[8];
    const float* bias2     = (const float*)d_in[9];

    const int  CIN = 128, F1 = 50, F2 = 40;
    const int  KP1 = 128, FP1 = 56;            // padded W1T dims
    const int  KP2 = 52,  FP2 = 40;            // padded W2T dims
    const int  N = in_sizes[0] / CIN;          // 100000
    const long E = in_sizes[1] / 2;            // 3200000
    const int* src = edge_idx;
    const int* dst = edge_idx + E;
    const long TOT = E + N;                    // edges incl self-loops
    const int  NB = (N + RNODES - 1) >> RBITS; // 391 buckets (<=512)

    // ---- workspace layout ----
    char* wsb = (char*)d_ws;
    size_t regionA = (size_t)NB * CAP * 4;                        // 14.4 MB
    if ((size_t)N * HS * 4 > regionA) regionA = (size_t)N * HS * 4;
    int*      binned = (int*)wsb;
    unsigned* hb     = (unsigned*)wsb;
    float*    hout   = (float*)(wsb + regionA);         // N*HOS floats (22.4 MB)
    float*    as_    = hout + (long)N * HOS;            // N
    float*    ad_    = as_ + N;                         // N
    int*      starts  = (int*)(ad_ + N);                // N+1
    int*      csr_src = starts + (N + 1);               // TOT
    int*      bstarts = csr_src + TOT;                  // NB+1
    int*      bcursor = bstarts + (NB + 1);             // NB
    float*    WT1     = (float*)(bcursor + NB + 3);     // FP1*KP1
    float*    WT2     = WT1 + FP1 * KP1;                // FP2*KP2

    float* out_h = (float*)d_out;              // N*F2
    float* out_e = out_h + (long)N * F2;       // 2*E

    const int B = 256;
    const int nTileBlocks = (N + 63) / 64;     // gemm: 64-node tiles
    const int nBinBlocks = (int)((TOT + CHUNK - 1) / CHUNK);
    const int prepElems = FP1 * KP1 + FP2 * KP2 + NB;

    // ---- prep (WT transposes + cursor zero) + CSR build ----
    prep<<<dim3((prepElems + B - 1) / B), dim3(B), 0, stream>>>(
        W1, WT1, W2, WT2, bcursor, CIN, F1, KP1, FP1, F1, F2, KP2, FP2, NB);
    binning<<<dim3(nBinBlocks), dim3(512), 0, stream>>>(src, dst, bcursor, binned, E, N, TOT);
    bucket_scan<<<dim3(1), dim3(512), 0, stream>>>(bcursor, bstarts, starts, NB, N, (int)TOT);
    bucket_csr<<<dim3(NB), dim3(512), 0, stream>>>(binned, bstarts, starts, csr_src, N);

    // ---- layer 1 ----
    gemm_tile<KP1, F1, FP1 / 2, CIN><<<dim3(nTileBlocks), dim3(512), 0, stream>>>(
        x, WT1, att_src1, att_dst1, hb, as_, ad_, N);
    gat_gather<F1, HOS><<<dim3(N), dim3(64), 0, stream>>>(
        csr_src, starts, as_, ad_, hb, bias1, hout, N);

    // ---- layer 2 ----
    gemm_tile<KP2, F2, FP2 / 2, HOS><<<dim3(nTileBlocks), dim3(512), 0, stream>>>(
        hout, WT2, att_src2, att_dst2, hb, as_, ad_, N);
    gat_gather<F2, F2><<<dim3(N), dim3(64), 0, stream>>>(
        csr_src, starts, as_, ad_, hb, bias2, out_h, N);

    // ---- edge_index passthrough ----
    long n_e = 2 * E;
    long n4  = n_e / 4;
    copy_edges4<<<dim3((int)((n4 + B - 1) / B)), dim3(B), 0, stream>>>((const int4*)edge_idx, (float4*)out_e, n4);
    if (n_e - n4 * 4 > 0)
        copy_edges_tail<<<dim3(1), dim3(B), 0, stream>>>(edge_idx, out_e, n4 * 4, n_e);
}

// Round 12
// 371.297 us; speedup vs baseline: 2.9109x; 1.0557x over previous
//
#include <hip/hip_runtime.h>
#include <hip/hip_bf16.h>
#include <math.h>

#define NEG_SLOPE 0.2f
#define RBITS 8
#define RNODES 256          // nodes per bucket
#define CHUNK 8192          // edges per binning block
#define CAP   9216          // per-bucket region capacity (mean 8440 + ~8 sigma)
#define HS    32            // hb row stride in uints (128 B, line-aligned)
#define HOS   52            // hout row stride in floats (208 B, 16B-aligned, = KP2)

// ---------------- helpers ----------------

__device__ __forceinline__ float waveReduceSum(float v) {
    #pragma unroll
    for (int off = 32; off > 0; off >>= 1) v += __shfl_xor(v, off);
    return v;
}

__device__ __forceinline__ unsigned pack_bf16(float a, float b) {
    __hip_bfloat162 p(__float2bfloat16(a), __float2bfloat16(b));
    return *reinterpret_cast<unsigned*>(&p);
}
__device__ __forceinline__ float bf16lo_f(unsigned u) { return __uint_as_float(u << 16); }
__device__ __forceinline__ float bf16hi_f(unsigned u) { return __uint_as_float(u & 0xFFFF0000u); }

// ---------------- fused prep: WT1, WT2 transpose + bcursor zero ----------------

__global__ void prep(const float* __restrict__ W1, float* __restrict__ WT1,
                     const float* __restrict__ W2, float* __restrict__ WT2,
                     int* __restrict__ bcursor,
                     int K1, int F1, int KP1, int FP1,
                     int K2, int F2, int KP2, int FP2, int NB) {
    int i = blockIdx.x * blockDim.x + threadIdx.x;
    int z1 = FP1 * KP1, z2 = FP2 * KP2;
    if (i < z1) {
        int f = i / KP1, k = i - f * KP1;
        WT1[i] = (f < F1 && k < K1) ? W1[k * F1 + f] : 0.f;
    } else if (i < z1 + z2) {
        int j = i - z1;
        int f = j / KP2, k = j - f * KP2;
        WT2[j] = (f < F2 && k < K2) ? W2[k * F2 + f] : 0.f;
    } else if (i < z1 + z2 + NB) {
        bcursor[i - z1 - z2] = 0;
    }
}

// ---------------- CSR build ----------------

// bin edges into fixed-capacity bucket regions; pack (dst&255)<<17 | src
__global__ __launch_bounds__(512) void binning(
        const int* __restrict__ src, const int* __restrict__ dst,
        int* __restrict__ bcursor, int* __restrict__ binned,
        long E, int N, long TOT) {
    __shared__ int hist[512];
    __shared__ int base[512];
    int t = threadIdx.x;
    hist[t] = 0;
    __syncthreads();
    long c0 = blockIdx.x * (long)CHUNK;
    long c1 = c0 + CHUNK; if (c1 > TOT) c1 = TOT;
    for (long i = c0 + t; i < c1; i += 512) {
        int d = (i < E) ? dst[i] : (int)(i - E);
        atomicAdd(&hist[d >> RBITS], 1);
    }
    __syncthreads();
    {
        int c = hist[t];
        base[t] = c ? atomicAdd(&bcursor[t], c) : 0;
        hist[t] = 0;
    }
    __syncthreads();
    for (long i = c0 + t; i < c1; i += 512) {
        int s, d;
        if (i < E) { s = src[i]; d = dst[i]; } else { s = d = (int)(i - E); }
        int b = d >> RBITS;
        int p = base[b] + atomicAdd(&hist[b], 1);
        if (p >= CAP) p = CAP - 1;   // safety clamp (never hit for this input)
        binned[(long)b * CAP + p] = ((d & (RNODES - 1)) << 17) | s;
    }
}

// single block (512 thr): exclusive scan of bucket counts (bcursor) -> bstarts[0..NB]
__global__ __launch_bounds__(512) void bucket_scan(
        const int* __restrict__ bcursor, int* __restrict__ bstarts,
        int* __restrict__ starts, int NB, int N, int TOT) {
    __shared__ int s[512];
    int t = threadIdx.x;
    int v = (t < NB) ? bcursor[t] : 0;
    s[t] = v;
    __syncthreads();
    for (int off = 1; off < 512; off <<= 1) {
        int u = (t >= off) ? s[t - off] : 0;
        __syncthreads();
        s[t] += u;
        __syncthreads();
    }
    int excl = s[t] - v;
    if (t < NB) bstarts[t] = excl;
    if (t == 0) { bstarts[NB] = TOT; starts[N] = TOT; }
}

// one block (512 thr) per bucket: per-node counts, LDS scan -> starts, compacting scatter
__global__ __launch_bounds__(512) void bucket_csr(
        const int* __restrict__ binned, const int* __restrict__ bstarts,
        int* __restrict__ starts, int* __restrict__ csr_src, int N) {
    __shared__ int cnt[RNODES];
    __shared__ int scn[RNODES];
    int b = blockIdx.x, t = threadIdx.x;
    int node0 = b << RBITS;
    int R = N - node0; if (R > RNODES) R = RNODES;
    int e0 = bstarts[b];
    int ecnt = bstarts[b + 1] - e0;
    const int* bin = binned + (long)b * CAP;
    if (t < RNODES) cnt[t] = 0;
    __syncthreads();
    for (int i = t; i < ecnt; i += 512)
        atomicAdd(&cnt[bin[i] >> 17], 1);
    __syncthreads();
    int v = (t < RNODES) ? cnt[t] : 0;
    if (t < RNODES) scn[t] = v;
    __syncthreads();
    for (int off = 1; off < RNODES; off <<= 1) {
        int u = (t >= off && t < RNODES) ? scn[t - off] : 0;
        __syncthreads();
        if (t < RNODES) scn[t] += u;
        __syncthreads();
    }
    if (t < RNODES) {
        int excl = scn[t] - v;
        if (t < R) starts[node0 + t] = e0 + excl;
        cnt[t] = excl;   // reuse as cursor
    }
    __syncthreads();
    for (int i = t; i < ecnt; i += 512) {
        int packed = bin[i];
        int ld = packed >> 17;
        int p = atomicAdd(&cnt[ld], 1);
        csr_src[e0 + p] = packed & 0x1FFFF;
    }
}

// ---------------- GEMM: lane=node, scalar W, LDS row-major x ----------------
// block = 512 thr = 8 waves; 64-node tile; wave w computes features 8w..8w+7.
// hb rows zero-padded through uint FPH-1 (acc==0 for f>=F since WT zero-padded).
// r11: vec4 global staging (gemm was staging-bound: r4 VALUBusy 19%).
// r12: xT stored ROW-MAJOR per node, padded +4 floats (+1 uint4): lane reads
// its own row with ds_read_b128 (32 instrs vs 128 ds_read_b32 at the old
// [k][node] layout); lane uint4-stride = KP/4+1 (odd) -> conflict-free.
// Staging is a straight float4 copy (b128 write, consecutive lanes ->
// consecutive uint4 slots).
template <int KP, int F, int FPH, int XS>
__global__ __launch_bounds__(512) void gemm_tile(
        const float* __restrict__ x, const float* __restrict__ WT,
        const float* __restrict__ att_s, const float* __restrict__ att_d,
        unsigned* __restrict__ hb, float* __restrict__ as_, float* __restrict__ ad_,
        int N) {
    static_assert(KP % 4 == 0 && XS % 4 == 0 && XS >= KP, "vec4 staging");
    constexpr int Q4 = KP / 4;
    constexpr int RS = KP + 4;              // xT row stride in floats (odd uint4 stride)
    __shared__ float xT[64 * RS];
    __shared__ float asl[64], adl[64];
    int t = threadIdx.x;
    int lane = t & 63;
    int w = t >> 6;
    long n0 = (long)blockIdx.x * 64;
    int n = (int)n0 + lane;

    if (t < 64) { asl[t] = 0.f; adl[t] = 0.f; }
    for (int idx = t; idx < Q4 * 64; idx += 512) {
        int nn = idx / Q4;
        int k4 = (idx - nn * Q4) * 4;
        float4 v = make_float4(0.f, 0.f, 0.f, 0.f);
        if (n0 + nn < N) v = *(const float4*)(x + (n0 + nn) * (long)XS + k4);
        *(float4*)(xT + nn * RS + k4) = v;
    }
    __syncthreads();

    int f0 = __builtin_amdgcn_readfirstlane(w * 8);
    float acc[8] = {0.f, 0.f, 0.f, 0.f, 0.f, 0.f, 0.f, 0.f};
    if (f0 < F) {
        const float* xrow = xT + lane * RS;
        const float* wbase = WT + (long)f0 * KP;
        for (int k0 = 0; k0 < KP; k0 += 4) {
            float4 xv = *(const float4*)(xrow + k0);
            #pragma unroll
            for (int j = 0; j < 8; ++j) {
                const float* wr = wbase + j * KP + k0;   // wave-uniform -> s_load
                float a = acc[j];
                a = fmaf(wr[0], xv.x, a);
                a = fmaf(wr[1], xv.y, a);
                a = fmaf(wr[2], xv.z, a);
                a = fmaf(wr[3], xv.w, a);
                acc[j] = a;
            }
        }
        float ps = 0.f, pd = 0.f;
        #pragma unroll
        for (int j = 0; j < 8; ++j) {
            float sa = (f0 + j < F) ? att_s[f0 + j] : 0.f;
            float da = (f0 + j < F) ? att_d[f0 + j] : 0.f;
            ps = fmaf(acc[j], sa, ps);
            pd = fmaf(acc[j], da, pd);
        }
        atomicAdd(&asl[lane], ps);
        atomicAdd(&adl[lane], pd);
    }
    __syncthreads();

    if (f0 < F && n < N) {
        int f0h = f0 >> 1;
        #pragma unroll
        for (int q = 0; q < 4; ++q) {
            int fp = f0h + q;
            if (fp < FPH) hb[(long)n * HS + fp] = pack_bf16(acc[2 * q], acc[2 * q + 1]);
        }
    }
    if (w == 0 && n < N) { as_[n] = asl[lane]; ad_[n] = adl[lane]; }
}

// ---------------- gat gather ----------------
// one wave per dst node: single-pass softmax (|e| small; exp safe).
// OCTET layout: 8 lanes per edge (group g = lane>>3), lane fl = lane&7 loads
// uint4 (8 bf16 features). Round-10 body (best gat: 70.0 us): 1-wave blocks
// <<<N,64>>>, degree-matched work (r2), no min-waves clause (r1), phase-A
// batched w computation overlapping gathers (r5/r7), no extra pass (r6).
// OST: output row stride; pads (F..OST) written ZERO so gemm2 can vec4-stage.
// r12: OST=52 (=KP2) instead of 56 -> lane fl=6 writes 1 pad float2 instead
// of 3 (r11's gat1 occupancy regression 78->69%).
template <int F, int OST>
__global__ __launch_bounds__(64) void gat_gather(
                           const int* __restrict__ csr_src, const int* __restrict__ starts,
                           const float* __restrict__ as_, const float* __restrict__ ad_,
                           const unsigned* __restrict__ hb, const float* __restrict__ bias,
                           float* __restrict__ out, int N) {
    constexpr int NU4 = (F + 7) / 8;        // uint4 per row: 7 (F=50) / 5 (F=40)
    int lane = threadIdx.x & 63;
    int g  = lane >> 3;                     // octet (edge slot) 0..7
    int fl = lane & 7;                      // feature lane
    bool actf = (fl < NU4);
    long wave = (blockIdx.x * (long)blockDim.x + threadIdx.x) >> 6;
    if (wave >= N) return;
    int d = (int)wave;
    int s0 = starts[d], s1 = starts[d + 1];
    float add = ad_[d];
    const unsigned* hbase = hb + 4 * fl;    // lane-fixed feature offset (16B aligned)

    float lsum = 0.f;
    float a0 = 0.f, a1 = 0.f, a2 = 0.f, a3 = 0.f;
    float a4 = 0.f, a5 = 0.f, a6 = 0.f, a7 = 0.f;

    for (int base = s0; base < s1; base += 64) {
        int k = base + lane;
        int s = (k < s1) ? csr_src[k] : 0;        // invalid lanes -> row 0 (w=0 later)
        unsigned soff = (unsigned)s << 5;         // row offset in uints (HS=32)
        float e = as_[s] + add;
        e = e > 0.f ? e : NEG_SLOPE * e;
        float w = (k < s1) ? __expf(e) : 0.f;
        lsum += w;
        int cnt = min(64, s1 - base);
        int nst = (cnt + 7) >> 3;                 // octet steps (1..8)
        int j = 0;
        for (; j + 4 <= nst; j += 4) {
            int i0 = 8 * j + g;
            unsigned so0 = __shfl(soff, i0);
            unsigned so1 = __shfl(soff, i0 + 8);
            unsigned so2 = __shfl(soff, i0 + 16);
            unsigned so3 = __shfl(soff, i0 + 24);
            uint4 h0 = make_uint4(0u,0u,0u,0u), h1 = h0, h2 = h0, h3 = h0;
            if (actf) {
                h0 = *(const uint4*)(hbase + so0);
                h1 = *(const uint4*)(hbase + so1);
                h2 = *(const uint4*)(hbase + so2);
                h3 = *(const uint4*)(hbase + so3);
            }
            float w0 = __shfl(w, i0);
            float w1 = __shfl(w, i0 + 8);
            float w2 = __shfl(w, i0 + 16);
            float w3 = __shfl(w, i0 + 24);
            a0 = fmaf(w0, bf16lo_f(h0.x), a0); a1 = fmaf(w0, bf16hi_f(h0.x), a1);
            a2 = fmaf(w0, bf16lo_f(h0.y), a2); a3 = fmaf(w0, bf16hi_f(h0.y), a3);
            a4 = fmaf(w0, bf16lo_f(h0.z), a4); a5 = fmaf(w0, bf16hi_f(h0.z), a5);
            a6 = fmaf(w0, bf16lo_f(h0.w), a6); a7 = fmaf(w0, bf16hi_f(h0.w), a7);
            a0 = fmaf(w1, bf16lo_f(h1.x), a0); a1 = fmaf(w1, bf16hi_f(h1.x), a1);
            a2 = fmaf(w1, bf16lo_f(h1.y), a2); a3 = fmaf(w1, bf16hi_f(h1.y), a3);
            a4 = fmaf(w1, bf16lo_f(h1.z), a4); a5 = fmaf(w1, bf16hi_f(h1.z), a5);
            a6 = fmaf(w1, bf16lo_f(h1.w), a6); a7 = fmaf(w1, bf16hi_f(h1.w), a7);
            a0 = fmaf(w2, bf16lo_f(h2.x), a0); a1 = fmaf(w2, bf16hi_f(h2.x), a1);
            a2 = fmaf(w2, bf16lo_f(h2.y), a2); a3 = fmaf(w2, bf16hi_f(h2.y), a3);
            a4 = fmaf(w2, bf16lo_f(h2.z), a4); a5 = fmaf(w2, bf16hi_f(h2.z), a5);
            a6 = fmaf(w2, bf16lo_f(h2.w), a6); a7 = fmaf(w2, bf16hi_f(h2.w), a7);
            a0 = fmaf(w3, bf16lo_f(h3.x), a0); a1 = fmaf(w3, bf16hi_f(h3.x), a1);
            a2 = fmaf(w3, bf16lo_f(h3.y), a2); a3 = fmaf(w3, bf16hi_f(h3.y), a3);
            a4 = fmaf(w3, bf16lo_f(h3.z), a4); a5 = fmaf(w3, bf16hi_f(h3.z), a5);
            a6 = fmaf(w3, bf16lo_f(h3.w), a6); a7 = fmaf(w3, bf16hi_f(h3.w), a7);
        }
        for (; j < nst; ++j) {
            int idx = 8 * j + g;
            float wp = __shfl(w, idx);
            unsigned so = __shfl(soff, idx);
            if (actf) {
                uint4 hv = *(const uint4*)(hbase + so);
                a0 = fmaf(wp, bf16lo_f(hv.x), a0); a1 = fmaf(wp, bf16hi_f(hv.x), a1);
                a2 = fmaf(wp, bf16lo_f(hv.y), a2); a3 = fmaf(wp, bf16hi_f(hv.y), a3);
                a4 = fmaf(wp, bf16lo_f(hv.z), a4); a5 = fmaf(wp, bf16hi_f(hv.z), a5);
                a6 = fmaf(wp, bf16lo_f(hv.w), a6); a7 = fmaf(wp, bf16hi_f(hv.w), a7);
            }
        }
    }

    // combine the eight octet partials (feature f = 8*fl + i lives in all groups)
    #pragma unroll
    for (int off = 8; off < 64; off <<= 1) {
        a0 += __shfl_xor(a0, off); a1 += __shfl_xor(a1, off);
        a2 += __shfl_xor(a2, off); a3 += __shfl_xor(a3, off);
        a4 += __shfl_xor(a4, off); a5 += __shfl_xor(a5, off);
        a6 += __shfl_xor(a6, off); a7 += __shfl_xor(a7, off);
    }
    float l = waveReduceSum(lsum);

    if (actf) {
        float inv = 1.f / l;
        int fb = 8 * fl;
        float v[8] = {a0, a1, a2, a3, a4, a5, a6, a7};
        float2* orow = (float2*)(out + (long)d * OST + fb);   // 8B-aligned (OST even)
        #pragma unroll
        for (int i = 0; i < 8; i += 2) {
            if (fb + i < OST) {
                float u0 = 0.f, u1 = 0.f;
                if (fb + i < F) {            // F even -> pair fully valid
                    u0 = v[i]     * inv + bias[fb + i];
                    u1 = v[i + 1] * inv + bias[fb + i + 1];
                    u0 = u0 > 0.f ? u0 : 0.f;
                    u1 = u1 > 0.f ? u1 : 0.f;
                }
                orow[i >> 1] = make_float2(u0, u1);   // pads -> 0 (gemm2 vec4 safety)
            }
        }
    }
}

// edge_index passthrough as float (vectorized)
__global__ void copy_edges4(const int4* __restrict__ ei, float4* __restrict__ out, long n4) {
    long i = blockIdx.x * (long)blockDim.x + threadIdx.x;
    if (i < n4) {
        int4 v = ei[i];
        out[i] = make_float4((float)v.x, (float)v.y, (float)v.z, (float)v.w);
    }
}
__global__ void copy_edges_tail(const int* __restrict__ ei, float* __restrict__ out,
                                long lo, long n) {
    long i = lo + blockIdx.x * (long)blockDim.x + threadIdx.x;
    if (i < n) out[i] = (float)ei[i];
}

// ---------------- launch ----------------

extern "C" void kernel_launch(void* const* d_in, const int* in_sizes, int n_in,
                              void* d_out, int out_size, void* d_ws, size_t ws_size,
                              hipStream_t stream) {
    const float* x         = (const float*)d_in[0];
    const int*   edge_idx  = (const int*)d_in[1];
    const float* W1        = (const float*)d_in[2];
    const float* att_src1  = (const float*)d_in[3];
    const float* att_dst1  = (const float*)d_in[4];
    const float* bias1     = (const float*)d_in[5];
    const float* W2        = (const float*)d_in[6];
    const float* att_src2  = (const float*)d_in[7];
    const float* att_dst2  = (const float*)d_in[8];
    const float* bias2     = (const float*)d_in[9];

    const int  CIN = 128, F1 = 50, F2 = 40;
    const int  KP1 = 128, FP1 = 56;            // padded W1T dims
    const int  KP2 = 52,  FP2 = 40;            // padded W2T dims
    const int  N = in_sizes[0] / CIN;          // 100000
    const long E = in_sizes[1] / 2;            // 3200000
    const int* src = edge_idx;
    const int* dst = edge_idx + E;
    const long TOT = E + N;                    // edges incl self-loops
    const int  NB = (N + RNODES - 1) >> RBITS; // 391 buckets (<=512)

    // ---- workspace layout ----
    char* wsb = (char*)d_ws;
    size_t regionA = (size_t)NB * CAP * 4;                        // 14.4 MB
    if ((size_t)N * HS * 4 > regionA) regionA = (size_t)N * HS * 4;
    int*      binned = (int*)wsb;
    unsigned* hb     = (unsigned*)wsb;
    float*    hout   = (float*)(wsb + regionA);         // N*HOS floats (20.8 MB)
    float*    as_    = hout + (long)N * HOS;            // N
    float*    ad_    = as_ + N;                         // N
    int*      starts  = (int*)(ad_ + N);                // N+1
    int*      csr_src = starts + (N + 1);               // TOT
    int*      bstarts = csr_src + TOT;                  // NB+1
    int*      bcursor = bstarts + (NB + 1);             // NB
    float*    WT1     = (float*)(bcursor + NB + 3);     // FP1*KP1
    float*    WT2     = WT1 + FP1 * KP1;                // FP2*KP2

    float* out_h = (float*)d_out;              // N*F2
    float* out_e = out_h + (long)N * F2;       // 2*E

    const int B = 256;
    const int nTileBlocks = (N + 63) / 64;     // gemm: 64-node tiles
    const int nBinBlocks = (int)((TOT + CHUNK - 1) / CHUNK);
    const int prepElems = FP1 * KP1 + FP2 * KP2 + NB;

    // ---- prep (WT transposes + cursor zero) + CSR build ----
    prep<<<dim3((prepElems + B - 1) / B), dim3(B), 0, stream>>>(
        W1, WT1, W2, WT2, bcursor, CIN, F1, KP1, FP1, F1, F2, KP2, FP2, NB);
    binning<<<dim3(nBinBlocks), dim3(512), 0, stream>>>(src, dst, bcursor, binned, E, N, TOT);
    bucket_scan<<<dim3(1), dim3(512), 0, stream>>>(bcursor, bstarts, starts, NB, N, (int)TOT);
    bucket_csr<<<dim3(NB), dim3(512), 0, stream>>>(binned, bstarts, starts, csr_src, N);

    // ---- layer 1 ----
    gemm_tile<KP1, F1, FP1 / 2, CIN><<<dim3(nTileBlocks), dim3(512), 0, stream>>>(
        x, WT1, att_src1, att_dst1, hb, as_, ad_, N);
    gat_gather<F1, HOS><<<dim3(N), dim3(64), 0, stream>>>(
        csr_src, starts, as_, ad_, hb, bias1, hout, N);

    // ---- layer 2 ----
    gemm_tile<KP2, F2, FP2 / 2, HOS><<<dim3(nTileBlocks), dim3(512), 0, stream>>>(
        hout, WT2, att_src2, att_dst2, hb, as_, ad_, N);
    gat_gather<F2, F2><<<dim3(N), dim3(64), 0, stream>>>(
        csr_src, starts, as_, ad_, hb, bias2, out_h, N);

    // ---- edge_index passthrough ----
    long n_e = 2 * E;
    long n4  = n_e / 4;
    copy_edges4<<<dim3((int)((n4 + B - 1) / B)), dim3(B), 0, stream>>>((const int4*)edge_idx, (float4*)out_e, n4);
    if (n_e - n4 * 4 > 0)
        copy_edges_tail<<<dim3(1), dim3(B), 0, stream>>>(edge_idx, out_e, n4 * 4, n_e);
}